// Round 2
// baseline (442.439 us; speedup 1.0000x reference)
//
#include <hip/hip_runtime.h>

typedef __bf16 bf16x8 __attribute__((ext_vector_type(8)));
typedef float  f32x4  __attribute__((ext_vector_type(4)));
typedef int    i32x4  __attribute__((ext_vector_type(4)));

#define DEVI __device__ __forceinline__

DEVI unsigned short f2bf(float f) {
    union { float f; unsigned u; } v; v.f = f;
    unsigned r = (v.u + 0x7fffu + ((v.u >> 16) & 1u)) >> 16;
    return (unsigned short)r;
}

// ---------------------------------------------------------------------------
// Transpose 1024x1024 f32 -> bf16:  WT[n][k] = W[k][n]
// ---------------------------------------------------------------------------
__global__ __launch_bounds__(256) void wtrans_kernel(const float* __restrict__ W,
                                                     unsigned short* __restrict__ WT) {
    __shared__ float tile[64][65];
    const int k0 = blockIdx.x * 64, n0 = blockIdx.y * 64;
    const int i = threadIdx.x;
    const int c4 = (i & 15) * 4, rbase = i >> 4;
    for (int rr = 0; rr < 4; ++rr) {
        const int kl = rbase + rr * 16;
        const float4 v = *(const float4*)(W + (size_t)(k0 + kl) * 1024 + n0 + c4);
        tile[kl][c4 + 0] = v.x; tile[kl][c4 + 1] = v.y;
        tile[kl][c4 + 2] = v.z; tile[kl][c4 + 3] = v.w;
    }
    __syncthreads();
    for (int rr = 0; rr < 4; ++rr) {
        const int nl = rbase + rr * 16;
        ushort4 o;
        o.x = f2bf(tile[c4 + 0][nl]); o.y = f2bf(tile[c4 + 1][nl]);
        o.z = f2bf(tile[c4 + 2][nl]); o.w = f2bf(tile[c4 + 3][nl]);
        *(ushort4*)(WT + (size_t)(n0 + nl) * 1024 + k0 + c4) = o;
    }
}

// ---------------------------------------------------------------------------
// Mask all-true flags per (b, 128-row t-tile, 64-col s-tile).
// mask is int32 (harness pushes bool as int). grid = 4 * 16 * 32 = 2048 blocks.
// Each thread checks 32 ints (8 x uint4).
// ---------------------------------------------------------------------------
__global__ __launch_bounds__(256) void maskflag_kernel(const int* __restrict__ mask,
                                                       unsigned char* __restrict__ flags) {
    const int bid = blockIdx.x;
    const int b = bid >> 9, rem = bid & 511;
    const int tb = rem >> 5, si = rem & 31;
    const int i = threadIdx.x;
    const int t = tb * 128 + (i >> 1);
    const int s = si * 64 + (i & 1) * 32;
    const uint4* p = (const uint4*)(mask + ((size_t)(b * 2048 + t)) * 2048 + s);
    int ok = 1;
    #pragma unroll
    for (int u = 0; u < 8; ++u) {
        const uint4 a = p[u];
        ok &= (a.x != 0) & (a.y != 0) & (a.z != 0) & (a.w != 0);
    }
    int all = __syncthreads_and(ok);
    if (i == 0) flags[bid] = (unsigned char)all;
}

// ---------------------------------------------------------------------------
// Projection GEMM: C[m,n] = A_f32[m,:] . WT_bf16[n,:] + bias[n]
// A: [8192][1024] f32, WT: [1024][1024] bf16 (row n, col k)
// Output: bf16 scattered to [b(4)][h(16)][t(2048)][c(64)], m=b*2048+t, n=h*64+c
// ---------------------------------------------------------------------------
__global__ __launch_bounds__(256) void proj_gemm_kernel(const float* __restrict__ A,
                                                        const unsigned short* __restrict__ BT,
                                                        const float* __restrict__ bias,
                                                        unsigned short* __restrict__ O) {
    __shared__ __align__(16) unsigned short Ab[128 * 72];
    __shared__ __align__(16) unsigned short Bb[128 * 72];
    const int n0 = blockIdx.x * 128, m0 = blockIdx.y * 128;
    const int i = threadIdx.x, w = i >> 6, l = i & 63;
    const int wm = w >> 1, wn = w & 1;
    const int lrow = l & 15, lhi = l >> 4;
    const int arow = i >> 1, kseg = (i & 1) * 16;

    f32x4 acc[4][4] = {};

    for (int k0 = 0; k0 < 1024; k0 += 32) {
        // stage A (f32 -> bf16), row stride 72 elems (144B: 2-way bank alias, 16B aligned)
        {
            const float* src = A + (size_t)(m0 + arow) * 1024 + k0 + kseg;
            const float4 v0 = *(const float4*)(src);
            const float4 v1 = *(const float4*)(src + 4);
            const float4 v2 = *(const float4*)(src + 8);
            const float4 v3 = *(const float4*)(src + 12);
            i32x4 w0, w1;
            w0[0] = (int)(f2bf(v0.x) | ((unsigned)f2bf(v0.y) << 16));
            w0[1] = (int)(f2bf(v0.z) | ((unsigned)f2bf(v0.w) << 16));
            w0[2] = (int)(f2bf(v1.x) | ((unsigned)f2bf(v1.y) << 16));
            w0[3] = (int)(f2bf(v1.z) | ((unsigned)f2bf(v1.w) << 16));
            w1[0] = (int)(f2bf(v2.x) | ((unsigned)f2bf(v2.y) << 16));
            w1[1] = (int)(f2bf(v2.z) | ((unsigned)f2bf(v2.w) << 16));
            w1[2] = (int)(f2bf(v3.x) | ((unsigned)f2bf(v3.y) << 16));
            w1[3] = (int)(f2bf(v3.z) | ((unsigned)f2bf(v3.w) << 16));
            *(i32x4*)&Ab[arow * 72 + kseg]     = w0;
            *(i32x4*)&Ab[arow * 72 + kseg + 8] = w1;
        }
        // stage B (bf16 copy)
        {
            const unsigned short* src = BT + (size_t)(n0 + arow) * 1024 + k0 + kseg;
            const i32x4 v0 = *(const i32x4*)(src);
            const i32x4 v1 = *(const i32x4*)(src + 8);
            *(i32x4*)&Bb[arow * 72 + kseg]     = v0;
            *(i32x4*)&Bb[arow * 72 + kseg + 8] = v1;
        }
        __syncthreads();
        bf16x8 af[4], bfr[4];
        #pragma unroll
        for (int mf = 0; mf < 4; ++mf)
            af[mf] = *(const bf16x8*)&Ab[(wm * 64 + mf * 16 + lrow) * 72 + lhi * 8];
        #pragma unroll
        for (int nf = 0; nf < 4; ++nf)
            bfr[nf] = *(const bf16x8*)&Bb[(wn * 64 + nf * 16 + lrow) * 72 + lhi * 8];
        #pragma unroll
        for (int mf = 0; mf < 4; ++mf)
            #pragma unroll
            for (int nf = 0; nf < 4; ++nf)
                acc[mf][nf] = __builtin_amdgcn_mfma_f32_16x16x32_bf16(af[mf], bfr[nf], acc[mf][nf], 0, 0, 0);
        __syncthreads();
    }

    #pragma unroll
    for (int nf = 0; nf < 4; ++nf) {
        const int n = n0 + wn * 64 + nf * 16 + lrow;
        const float bv = bias[n];
        const int h = n >> 6, c = n & 63;
        #pragma unroll
        for (int mf = 0; mf < 4; ++mf) {
            #pragma unroll
            for (int r = 0; r < 4; ++r) {
                const int m = m0 + wm * 64 + mf * 16 + lhi * 4 + r;
                const int b = m >> 11, t = m & 2047;
                O[(((size_t)(b * 16 + h)) * 2048 + t) * 64 + c] = f2bf(acc[mf][nf][r] + bv);
            }
        }
    }
}

// ---------------------------------------------------------------------------
// Final GEMM: out[m,n] = attn_bf16[m,:] . WoT_bf16[n,:] + bo[n]   (f32 out)
// ---------------------------------------------------------------------------
__global__ __launch_bounds__(256) void final_gemm_kernel(const unsigned short* __restrict__ A,
                                                         const unsigned short* __restrict__ BT,
                                                         const float* __restrict__ bias,
                                                         float* __restrict__ O) {
    __shared__ __align__(16) unsigned short Ab[128 * 72];
    __shared__ __align__(16) unsigned short Bb[128 * 72];
    const int n0 = blockIdx.x * 128, m0 = blockIdx.y * 128;
    const int i = threadIdx.x, w = i >> 6, l = i & 63;
    const int wm = w >> 1, wn = w & 1;
    const int lrow = l & 15, lhi = l >> 4;
    const int arow = i >> 1, kseg = (i & 1) * 16;

    f32x4 acc[4][4] = {};

    for (int k0 = 0; k0 < 1024; k0 += 32) {
        {
            const unsigned short* src = A + (size_t)(m0 + arow) * 1024 + k0 + kseg;
            const i32x4 v0 = *(const i32x4*)(src);
            const i32x4 v1 = *(const i32x4*)(src + 8);
            *(i32x4*)&Ab[arow * 72 + kseg]     = v0;
            *(i32x4*)&Ab[arow * 72 + kseg + 8] = v1;
        }
        {
            const unsigned short* src = BT + (size_t)(n0 + arow) * 1024 + k0 + kseg;
            const i32x4 v0 = *(const i32x4*)(src);
            const i32x4 v1 = *(const i32x4*)(src + 8);
            *(i32x4*)&Bb[arow * 72 + kseg]     = v0;
            *(i32x4*)&Bb[arow * 72 + kseg + 8] = v1;
        }
        __syncthreads();
        bf16x8 af[4], bfr[4];
        #pragma unroll
        for (int mf = 0; mf < 4; ++mf)
            af[mf] = *(const bf16x8*)&Ab[(wm * 64 + mf * 16 + lrow) * 72 + lhi * 8];
        #pragma unroll
        for (int nf = 0; nf < 4; ++nf)
            bfr[nf] = *(const bf16x8*)&Bb[(wn * 64 + nf * 16 + lrow) * 72 + lhi * 8];
        #pragma unroll
        for (int mf = 0; mf < 4; ++mf)
            #pragma unroll
            for (int nf = 0; nf < 4; ++nf)
                acc[mf][nf] = __builtin_amdgcn_mfma_f32_16x16x32_bf16(af[mf], bfr[nf], acc[mf][nf], 0, 0, 0);
        __syncthreads();
    }

    #pragma unroll
    for (int nf = 0; nf < 4; ++nf) {
        const int n = n0 + wn * 64 + nf * 16 + lrow;
        const float bv = bias[n];
        #pragma unroll
        for (int mf = 0; mf < 4; ++mf) {
            #pragma unroll
            for (int r = 0; r < 4; ++r) {
                const int m = m0 + wm * 64 + mf * 16 + lhi * 4 + r;
                O[(size_t)m * 1024 + n] = acc[mf][nf][r] + bv;
            }
        }
    }
}

// ---------------------------------------------------------------------------
// Flash attention. grid = (T/128 = 16, B*H = 64), 256 threads (4 waves).
// Each wave owns 32 Q rows. KV tiles of 64. Q/K/V are bf16 [bh][2048][64].
// ---------------------------------------------------------------------------
__global__ __launch_bounds__(256) void attn_kernel(const unsigned short* __restrict__ Qp,
                                                   const unsigned short* __restrict__ Kp,
                                                   const unsigned short* __restrict__ Vp,
                                                   const int* __restrict__ mask,
                                                   const unsigned char* __restrict__ flags,
                                                   unsigned short* __restrict__ attnb) {
    __shared__ __align__(16) unsigned short Kt[64 * 72];   // [s][k], stride 72
    __shared__ __align__(16) unsigned short Vt[64 * 72];   // [v][s], stride 72
    __shared__ __align__(16) unsigned short Pl[4][32 * 72];// per-wave [t][s]

    const int tb = blockIdx.x;
    const int bh = blockIdx.y;
    const int b = bh >> 4, h = bh & 15;
    const int i = threadIdx.x, w = i >> 6, l = i & 63;
    const int lrow = l & 15, lhi = l >> 4;

    const unsigned short* Qb = Qp + (size_t)bh * 2048 * 64;
    const unsigned short* Kb = Kp + (size_t)bh * 2048 * 64;
    const unsigned short* Vb = Vp + (size_t)bh * 2048 * 64;

    const int twave = tb * 128 + w * 32;

    bf16x8 qf[2][2];
    #pragma unroll
    for (int mg = 0; mg < 2; ++mg)
        #pragma unroll
        for (int ks = 0; ks < 2; ++ks)
            qf[mg][ks] = *(const bf16x8*)(Qb + (size_t)(twave + mg * 16 + lrow) * 64 + ks * 32 + lhi * 8);

    f32x4 o[2][4] = {};
    float mrow[2][4], lsum[2][4];
    #pragma unroll
    for (int mg = 0; mg < 2; ++mg)
        #pragma unroll
        for (int r = 0; r < 4; ++r) { mrow[mg][r] = -1e30f; lsum[mg][r] = 0.f; }

    const int srow = i >> 2, soff = (i & 3) * 16;

    for (int it = 0; it < 32; ++it) {
        const int s0 = it * 64;
        // stage K [s][k]
        {
            const unsigned short* src = Kb + (size_t)(s0 + srow) * 64 + soff;
            const i32x4 v0 = *(const i32x4*)(src);
            const i32x4 v1 = *(const i32x4*)(src + 8);
            *(i32x4*)&Kt[srow * 72 + soff]     = v0;
            *(i32x4*)&Kt[srow * 72 + soff + 8] = v1;
        }
        // stage V transposed -> Vt[v][s]
        {
            const unsigned short* src = Vb + (size_t)(s0 + srow) * 64 + soff;
            #pragma unroll
            for (int u = 0; u < 2; ++u) {
                const i32x4 v = *(const i32x4*)(src + u * 8);
                const unsigned short* pv = (const unsigned short*)&v;
                #pragma unroll
                for (int j = 0; j < 8; ++j)
                    Vt[(soff + u * 8 + j) * 72 + srow] = pv[j];
            }
        }
        __syncthreads();

        // QK^T
        f32x4 sc[2][4] = {};
        bf16x8 kf[4][2];
        #pragma unroll
        for (int nf = 0; nf < 4; ++nf)
            #pragma unroll
            for (int ks = 0; ks < 2; ++ks)
                kf[nf][ks] = *(const bf16x8*)&Kt[(nf * 16 + lrow) * 72 + ks * 32 + lhi * 8];
        #pragma unroll
        for (int mg = 0; mg < 2; ++mg)
            #pragma unroll
            for (int nf = 0; nf < 4; ++nf)
                #pragma unroll
                for (int ks = 0; ks < 2; ++ks)
                    sc[mg][nf] = __builtin_amdgcn_mfma_f32_16x16x32_bf16(qf[mg][ks], kf[nf][ks], sc[mg][nf], 0, 0, 0);

        #pragma unroll
        for (int mg = 0; mg < 2; ++mg)
            #pragma unroll
            for (int nf = 0; nf < 4; ++nf)
                #pragma unroll
                for (int r = 0; r < 4; ++r)
                    sc[mg][nf][r] *= 0.125f;

        const int flg = flags[(b * 16 + tb) * 32 + it];
        if (!flg) {
            #pragma unroll
            for (int mg = 0; mg < 2; ++mg)
                #pragma unroll
                for (int nf = 0; nf < 4; ++nf)
                    #pragma unroll
                    for (int r = 0; r < 4; ++r) {
                        const int t = twave + mg * 16 + lhi * 4 + r;
                        const int s = s0 + nf * 16 + lrow;
                        if (mask[(size_t)(b * 2048 + t) * 2048 + s] == 0) sc[mg][nf][r] -= 10000.0f;
                    }
        }

        // online softmax
        #pragma unroll
        for (int mg = 0; mg < 2; ++mg) {
            float mnew[4], scl[4], ps[4];
            #pragma unroll
            for (int r = 0; r < 4; ++r) {
                float rm = fmaxf(fmaxf(sc[mg][0][r], sc[mg][1][r]), fmaxf(sc[mg][2][r], sc[mg][3][r]));
                #pragma unroll
                for (int d = 1; d < 16; d <<= 1) rm = fmaxf(rm, __shfl_xor(rm, d, 16));
                mnew[r] = fmaxf(mrow[mg][r], rm);
                scl[r]  = __expf(mrow[mg][r] - mnew[r]);
                mrow[mg][r] = mnew[r];
                ps[r] = 0.f;
            }
            #pragma unroll
            for (int nf = 0; nf < 4; ++nf)
                #pragma unroll
                for (int r = 0; r < 4; ++r) {
                    const float p = __expf(sc[mg][nf][r] - mnew[r]);
                    sc[mg][nf][r] = p;
                    ps[r] += p;
                }
            #pragma unroll
            for (int r = 0; r < 4; ++r) {
                float s = ps[r];
                #pragma unroll
                for (int d = 1; d < 16; d <<= 1) s += __shfl_xor(s, d, 16);
                lsum[mg][r] = lsum[mg][r] * scl[r] + s;
                #pragma unroll
                for (int vf = 0; vf < 4; ++vf) o[mg][vf][r] *= scl[r];
            }
            // write P (bf16) to per-wave LDS [t][s]
            #pragma unroll
            for (int nf = 0; nf < 4; ++nf)
                #pragma unroll
                for (int r = 0; r < 4; ++r)
                    Pl[w][(mg * 16 + lhi * 4 + r) * 72 + nf * 16 + lrow] = f2bf(sc[mg][nf][r]);
        }
        asm volatile("s_waitcnt lgkmcnt(0)" ::: "memory");

        // PV
        bf16x8 pa[2][2], vfr[4][2];
        #pragma unroll
        for (int mg = 0; mg < 2; ++mg)
            #pragma unroll
            for (int ks = 0; ks < 2; ++ks)
                pa[mg][ks] = *(const bf16x8*)&Pl[w][(mg * 16 + lrow) * 72 + ks * 32 + lhi * 8];
        #pragma unroll
        for (int vf = 0; vf < 4; ++vf)
            #pragma unroll
            for (int ks = 0; ks < 2; ++ks)
                vfr[vf][ks] = *(const bf16x8*)&Vt[(vf * 16 + lrow) * 72 + ks * 32 + lhi * 8];
        #pragma unroll
        for (int mg = 0; mg < 2; ++mg)
            #pragma unroll
            for (int vf = 0; vf < 4; ++vf)
                #pragma unroll
                for (int ks = 0; ks < 2; ++ks)
                    o[mg][vf] = __builtin_amdgcn_mfma_f32_16x16x32_bf16(pa[mg][ks], vfr[vf][ks], o[mg][vf], 0, 0, 0);

        __syncthreads();
    }

    // epilogue: O / l, write bf16 attn [b*2048+t][h*64+v]
    #pragma unroll
    for (int mg = 0; mg < 2; ++mg)
        #pragma unroll
        for (int vf = 0; vf < 4; ++vf)
            #pragma unroll
            for (int r = 0; r < 4; ++r) {
                const int t = twave + mg * 16 + lhi * 4 + r;
                const int v = vf * 16 + lrow;
                const float val = o[mg][vf][r] / lsum[mg][r];
                attnb[(size_t)(b * 2048 + t) * 1024 + h * 64 + v] = f2bf(val);
            }
}

// ---------------------------------------------------------------------------
extern "C" void kernel_launch(void* const* d_in, const int* in_sizes, int n_in,
                              void* d_out, int out_size, void* d_ws, size_t ws_size,
                              hipStream_t stream) {
    const float* query = (const float*)d_in[0];
    const float* value = (const float*)d_in[1];
    const int*   mask  = (const int*)d_in[2];
    const float* Wq = (const float*)d_in[3];
    const float* bq = (const float*)d_in[4];
    const float* Wk = (const float*)d_in[5];
    const float* bk = (const float*)d_in[6];
    const float* Wv = (const float*)d_in[7];
    const float* bv = (const float*)d_in[8];
    const float* Wo = (const float*)d_in[9];
    const float* bo = (const float*)d_in[10];

    char* ws = (char*)d_ws;
    unsigned short* WqT   = (unsigned short*)(ws + ((size_t)0  << 20));  // 2 MB
    unsigned short* WkT   = (unsigned short*)(ws + ((size_t)2  << 20));  // 2 MB
    unsigned short* WvT   = (unsigned short*)(ws + ((size_t)4  << 20));  // 2 MB
    unsigned short* WoT   = (unsigned short*)(ws + ((size_t)6  << 20));  // 2 MB
    unsigned short* Qp    = (unsigned short*)(ws + ((size_t)8  << 20));  // 16 MB
    unsigned short* Kp    = (unsigned short*)(ws + ((size_t)24 << 20));  // 16 MB
    unsigned short* Vp    = (unsigned short*)(ws + ((size_t)40 << 20));  // 16 MB
    unsigned short* attnb = (unsigned short*)(ws + ((size_t)56 << 20));  // 16 MB
    unsigned char*  flags = (unsigned char*) (ws + ((size_t)72 << 20));  // 2048 B

    dim3 tg(16, 16);
    wtrans_kernel<<<tg, 256, 0, stream>>>(Wq, WqT);
    wtrans_kernel<<<tg, 256, 0, stream>>>(Wk, WkT);
    wtrans_kernel<<<tg, 256, 0, stream>>>(Wv, WvT);
    wtrans_kernel<<<tg, 256, 0, stream>>>(Wo, WoT);
    maskflag_kernel<<<2048, 256, 0, stream>>>(mask, flags);

    dim3 gp(8, 64);
    proj_gemm_kernel<<<gp, 256, 0, stream>>>(query, WqT, bq, Qp);
    proj_gemm_kernel<<<gp, 256, 0, stream>>>(value, WkT, bk, Kp);
    proj_gemm_kernel<<<gp, 256, 0, stream>>>(value, WvT, bv, Vp);

    dim3 ga(16, 64);
    attn_kernel<<<ga, 256, 0, stream>>>(Qp, Kp, Vp, mask, flags, attnb);

    final_gemm_kernel<<<gp, 256, 0, stream>>>(attnb, WoT, bo, (float*)d_out);
}

// Round 3
// 309.972 us; speedup vs baseline: 1.4274x; 1.4274x over previous
//
#include <hip/hip_runtime.h>

typedef __bf16 bf16x8 __attribute__((ext_vector_type(8)));
typedef __bf16 bf16x4 __attribute__((ext_vector_type(4)));
typedef float  f32x4  __attribute__((ext_vector_type(4)));
typedef int    i32x4  __attribute__((ext_vector_type(4)));

#define DEVI __device__ __forceinline__

DEVI unsigned short f2bf(float f) {
    union { float f; unsigned u; } v; v.f = f;
    unsigned r = (v.u + 0x7fffu + ((v.u >> 16) & 1u)) >> 16;
    return (unsigned short)r;
}

// exp2 coefficient: softmax(x/8) -> exp2(x * 0.125 * log2(e))
#define C_EXP 0.18033688011112042f

// ---------------------------------------------------------------------------
// Transpose 1024x1024 f32 -> bf16:  WT[n][k] = W[k][n]
// ---------------------------------------------------------------------------
__global__ __launch_bounds__(256) void wtrans_kernel(const float* __restrict__ W,
                                                     unsigned short* __restrict__ WT) {
    __shared__ float tile[64][65];
    const int k0 = blockIdx.x * 64, n0 = blockIdx.y * 64;
    const int i = threadIdx.x;
    const int c4 = (i & 15) * 4, rbase = i >> 4;
    for (int rr = 0; rr < 4; ++rr) {
        const int kl = rbase + rr * 16;
        const float4 v = *(const float4*)(W + (size_t)(k0 + kl) * 1024 + n0 + c4);
        tile[kl][c4 + 0] = v.x; tile[kl][c4 + 1] = v.y;
        tile[kl][c4 + 2] = v.z; tile[kl][c4 + 3] = v.w;
    }
    __syncthreads();
    for (int rr = 0; rr < 4; ++rr) {
        const int nl = rbase + rr * 16;
        ushort4 o;
        o.x = f2bf(tile[c4 + 0][nl]); o.y = f2bf(tile[c4 + 1][nl]);
        o.z = f2bf(tile[c4 + 2][nl]); o.w = f2bf(tile[c4 + 3][nl]);
        *(ushort4*)(WT + (size_t)(n0 + nl) * 1024 + k0 + c4) = o;
    }
}

// ---------------------------------------------------------------------------
// Mask all-true flags per (b, 128-row t-tile, 64-col s-tile). mask is int32.
// ---------------------------------------------------------------------------
__global__ __launch_bounds__(256) void maskflag_kernel(const int* __restrict__ mask,
                                                       unsigned char* __restrict__ flags) {
    const int bid = blockIdx.x;
    const int b = bid >> 9, rem = bid & 511;
    const int tb = rem >> 5, si = rem & 31;
    const int i = threadIdx.x;
    const int t = tb * 128 + (i >> 1);
    const int s = si * 64 + (i & 1) * 32;
    const uint4* p = (const uint4*)(mask + ((size_t)(b * 2048 + t)) * 2048 + s);
    int ok = 1;
    #pragma unroll
    for (int u = 0; u < 8; ++u) {
        const uint4 a = p[u];
        ok &= (a.x != 0) & (a.y != 0) & (a.z != 0) & (a.w != 0);
    }
    int all = __syncthreads_and(ok);
    if (i == 0) flags[bid] = (unsigned char)all;
}

// ---------------------------------------------------------------------------
// Projection GEMM: C[m,n] = A_f32[m,:] . WT_bf16[n,:] + bias[n]
// VT_MODE=0: write bf16 to [b][h][t][c]   (Q, K layout)
// VT_MODE=1: write bf16 to [b][h][c][t]   (V^T layout, for attn PV)
// ---------------------------------------------------------------------------
template <int VT_MODE>
__global__ __launch_bounds__(256) void proj_gemm_kernel(const float* __restrict__ A,
                                                        const unsigned short* __restrict__ BT,
                                                        const float* __restrict__ bias,
                                                        unsigned short* __restrict__ O) {
    __shared__ __align__(16) unsigned short Ab[128 * 72];
    __shared__ __align__(16) unsigned short Bb[128 * 72];
    const int n0 = blockIdx.x * 128, m0 = blockIdx.y * 128;
    const int i = threadIdx.x, w = i >> 6, l = i & 63;
    const int wm = w >> 1, wn = w & 1;
    const int lrow = l & 15, lhi = l >> 4;
    const int arow = i >> 1, kseg = (i & 1) * 16;

    f32x4 acc[4][4] = {};

    for (int k0 = 0; k0 < 1024; k0 += 32) {
        {
            const float* src = A + (size_t)(m0 + arow) * 1024 + k0 + kseg;
            const float4 v0 = *(const float4*)(src);
            const float4 v1 = *(const float4*)(src + 4);
            const float4 v2 = *(const float4*)(src + 8);
            const float4 v3 = *(const float4*)(src + 12);
            i32x4 w0, w1;
            w0[0] = (int)(f2bf(v0.x) | ((unsigned)f2bf(v0.y) << 16));
            w0[1] = (int)(f2bf(v0.z) | ((unsigned)f2bf(v0.w) << 16));
            w0[2] = (int)(f2bf(v1.x) | ((unsigned)f2bf(v1.y) << 16));
            w0[3] = (int)(f2bf(v1.z) | ((unsigned)f2bf(v1.w) << 16));
            w1[0] = (int)(f2bf(v2.x) | ((unsigned)f2bf(v2.y) << 16));
            w1[1] = (int)(f2bf(v2.z) | ((unsigned)f2bf(v2.w) << 16));
            w1[2] = (int)(f2bf(v3.x) | ((unsigned)f2bf(v3.y) << 16));
            w1[3] = (int)(f2bf(v3.z) | ((unsigned)f2bf(v3.w) << 16));
            *(i32x4*)&Ab[arow * 72 + kseg]     = w0;
            *(i32x4*)&Ab[arow * 72 + kseg + 8] = w1;
        }
        {
            const unsigned short* src = BT + (size_t)(n0 + arow) * 1024 + k0 + kseg;
            const i32x4 v0 = *(const i32x4*)(src);
            const i32x4 v1 = *(const i32x4*)(src + 8);
            *(i32x4*)&Bb[arow * 72 + kseg]     = v0;
            *(i32x4*)&Bb[arow * 72 + kseg + 8] = v1;
        }
        __syncthreads();
        bf16x8 af[4], bfr[4];
        #pragma unroll
        for (int mf = 0; mf < 4; ++mf)
            af[mf] = *(const bf16x8*)&Ab[(wm * 64 + mf * 16 + lrow) * 72 + lhi * 8];
        #pragma unroll
        for (int nf = 0; nf < 4; ++nf)
            bfr[nf] = *(const bf16x8*)&Bb[(wn * 64 + nf * 16 + lrow) * 72 + lhi * 8];
        #pragma unroll
        for (int mf = 0; mf < 4; ++mf)
            #pragma unroll
            for (int nf = 0; nf < 4; ++nf)
                acc[mf][nf] = __builtin_amdgcn_mfma_f32_16x16x32_bf16(af[mf], bfr[nf], acc[mf][nf], 0, 0, 0);
        __syncthreads();
    }

    #pragma unroll
    for (int nf = 0; nf < 4; ++nf) {
        const int n = n0 + wn * 64 + nf * 16 + lrow;
        const float bv = bias[n];
        const int h = n >> 6, c = n & 63;
        #pragma unroll
        for (int mf = 0; mf < 4; ++mf) {
            const int mbase = m0 + wm * 64 + mf * 16 + lhi * 4;
            const int b = mbase >> 11, t = mbase & 2047;
            if (VT_MODE == 0) {
                #pragma unroll
                for (int r = 0; r < 4; ++r)
                    O[(((size_t)(b * 16 + h)) * 2048 + t + r) * 64 + c] = f2bf(acc[mf][nf][r] + bv);
            } else {
                f32x4 v;
                #pragma unroll
                for (int r = 0; r < 4; ++r) v[r] = acc[mf][nf][r] + bv;
                bf16x4 pv = __builtin_convertvector(v, bf16x4);
                *(bf16x4*)(O + (((size_t)(b * 16 + h)) * 64 + c) * 2048 + t) = pv;
            }
        }
    }
}

// ---------------------------------------------------------------------------
// Final GEMM: out[m,n] = attn_bf16[m,:] . WoT_bf16[n,:] + bo[n]   (f32 out)
// ---------------------------------------------------------------------------
__global__ __launch_bounds__(256) void final_gemm_kernel(const unsigned short* __restrict__ A,
                                                         const unsigned short* __restrict__ BT,
                                                         const float* __restrict__ bias,
                                                         float* __restrict__ O) {
    __shared__ __align__(16) unsigned short Ab[128 * 72];
    __shared__ __align__(16) unsigned short Bb[128 * 72];
    const int n0 = blockIdx.x * 128, m0 = blockIdx.y * 128;
    const int i = threadIdx.x, w = i >> 6, l = i & 63;
    const int wm = w >> 1, wn = w & 1;
    const int lrow = l & 15, lhi = l >> 4;
    const int arow = i >> 1, kseg = (i & 1) * 16;

    f32x4 acc[4][4] = {};

    for (int k0 = 0; k0 < 1024; k0 += 32) {
        {
            const unsigned short* src = A + (size_t)(m0 + arow) * 1024 + k0 + kseg;
            const i32x4 v0 = *(const i32x4*)(src);
            const i32x4 v1 = *(const i32x4*)(src + 8);
            *(i32x4*)&Ab[arow * 72 + kseg]     = v0;
            *(i32x4*)&Ab[arow * 72 + kseg + 8] = v1;
        }
        {
            const unsigned short* src = BT + (size_t)(n0 + arow) * 1024 + k0 + kseg;
            const i32x4 v0 = *(const i32x4*)(src);
            const i32x4 v1 = *(const i32x4*)(src + 8);
            *(i32x4*)&Bb[arow * 72 + kseg]     = v0;
            *(i32x4*)&Bb[arow * 72 + kseg + 8] = v1;
        }
        __syncthreads();
        bf16x8 af[4], bfr[4];
        #pragma unroll
        for (int mf = 0; mf < 4; ++mf)
            af[mf] = *(const bf16x8*)&Ab[(wm * 64 + mf * 16 + lrow) * 72 + lhi * 8];
        #pragma unroll
        for (int nf = 0; nf < 4; ++nf)
            bfr[nf] = *(const bf16x8*)&Bb[(wn * 64 + nf * 16 + lrow) * 72 + lhi * 8];
        #pragma unroll
        for (int mf = 0; mf < 4; ++mf)
            #pragma unroll
            for (int nf = 0; nf < 4; ++nf)
                acc[mf][nf] = __builtin_amdgcn_mfma_f32_16x16x32_bf16(af[mf], bfr[nf], acc[mf][nf], 0, 0, 0);
        __syncthreads();
    }

    #pragma unroll
    for (int nf = 0; nf < 4; ++nf) {
        const int n = n0 + wn * 64 + nf * 16 + lrow;
        const float bv = bias[n];
        #pragma unroll
        for (int mf = 0; mf < 4; ++mf) {
            #pragma unroll
            for (int r = 0; r < 4; ++r) {
                const int m = m0 + wm * 64 + mf * 16 + lhi * 4 + r;
                O[(size_t)m * 1024 + n] = acc[mf][nf][r] + bv;
            }
        }
    }
}

// ---------------------------------------------------------------------------
// Flash attention (swapped QK^T, no running max: scores bounded by ~12 after
// scaling since |q.k| <= |q||k| ~ 64, exp and f32 sum cannot overflow).
// grid = (16, 64), 256 threads (4 waves), wave owns 32 Q rows (2 n-tiles).
// Q,K: bf16 [bh][2048][64]; V^T: bf16 [bh][64][2048]. Output attnb bf16.
// All MFMA lane layouts: input frag row = l&15, k = (l>>4)*8+j;
// output row m = (l>>4)*4+r, col n = l&15.
// ---------------------------------------------------------------------------
__global__ __launch_bounds__(256) void attn_kernel(const unsigned short* __restrict__ Qp,
                                                   const unsigned short* __restrict__ Kp,
                                                   const unsigned short* __restrict__ VTp,
                                                   const int* __restrict__ mask,
                                                   const unsigned char* __restrict__ flags,
                                                   unsigned short* __restrict__ attnb) {
    __shared__ __align__(16) unsigned short Kt[64 * 72];    // [s][dk]
    __shared__ __align__(16) unsigned short Vt[64 * 72];    // [v][s]
    __shared__ __align__(16) unsigned short Pl[4][32 * 72]; // per-wave [t][s]

    const int tb = blockIdx.x;
    const int bh = blockIdx.y;
    const int b = bh >> 4, h = bh & 15;
    const int i = threadIdx.x, w = i >> 6, l = i & 63;
    const int c = l & 15, g = l >> 4;

    const unsigned short* Qb  = Qp  + (size_t)bh * 2048 * 64;
    const unsigned short* Kb  = Kp  + (size_t)bh * 2048 * 64;
    const unsigned short* VTb = VTp + (size_t)bh * 64 * 2048;

    const int twave = tb * 128 + w * 32;

    // Q as B-operand: lane holds Q[t = twave + tn*16 + c][dk = ks*32 + g*8 + j]
    bf16x8 qf[2][2];
    #pragma unroll
    for (int tn = 0; tn < 2; ++tn)
        #pragma unroll
        for (int ks = 0; ks < 2; ++ks)
            qf[tn][ks] = *(const bf16x8*)(Qb + (size_t)(twave + tn * 16 + c) * 64 + ks * 32 + g * 8);

    // O^T accumulators: o[vm][tn], lane: v = vm*16 + g*4 + r, t = twave + tn*16 + c
    f32x4 o[4][2] = {};
    f32x4 accl[2] = {};  // per-lane partial softmax denominator (per tn)

    const int srow = i >> 2, sseg = (i & 3) * 16;

    for (int it = 0; it < 32; ++it) {
        const int s0 = it * 64;
        // stage K tile [s][dk]
        {
            const unsigned short* src = Kb + (size_t)(s0 + srow) * 64 + sseg;
            *(i32x4*)&Kt[srow * 72 + sseg]     = *(const i32x4*)(src);
            *(i32x4*)&Kt[srow * 72 + sseg + 8] = *(const i32x4*)(src + 8);
        }
        // stage V^T tile [v][s] (linear copy from global V^T)
        {
            const unsigned short* src = VTb + (size_t)srow * 2048 + s0 + sseg;
            *(i32x4*)&Vt[srow * 72 + sseg]     = *(const i32x4*)(src);
            *(i32x4*)&Vt[srow * 72 + sseg + 8] = *(const i32x4*)(src + 8);
        }
        __syncthreads();

        // QK^T swapped: sc[sm][tn] = S^T tile; lane: s = sm*16 + g*4 + r, t = twave + tn*16 + c
        f32x4 sc[4][2] = {};
        bf16x8 kf[4][2];
        #pragma unroll
        for (int sm = 0; sm < 4; ++sm)
            #pragma unroll
            for (int ks = 0; ks < 2; ++ks)
                kf[sm][ks] = *(const bf16x8*)&Kt[(sm * 16 + c) * 72 + ks * 32 + g * 8];
        #pragma unroll
        for (int sm = 0; sm < 4; ++sm)
            #pragma unroll
            for (int tn = 0; tn < 2; ++tn)
                #pragma unroll
                for (int ks = 0; ks < 2; ++ks)
                    sc[sm][tn] = __builtin_amdgcn_mfma_f32_16x16x32_bf16(kf[sm][ks], qf[tn][ks], sc[sm][tn], 0, 0, 0);

        // mask (raw-score units: -10000 after the 1/8 scale == -80000 raw)
        const int flg = flags[(b * 16 + tb) * 32 + it];
        if (!flg) {
            #pragma unroll
            for (int sm = 0; sm < 4; ++sm)
                #pragma unroll
                for (int tn = 0; tn < 2; ++tn)
                    #pragma unroll
                    for (int r = 0; r < 4; ++r) {
                        const int t = twave + tn * 16 + c;
                        const int s = s0 + sm * 16 + g * 4 + r;
                        if (mask[(size_t)(b * 2048 + t) * 2048 + s] == 0) sc[sm][tn][r] -= 80000.0f;
                    }
        }

        // p = exp2(s * C); accumulate denominator; write P to per-wave LDS [t][s]
        #pragma unroll
        for (int sm = 0; sm < 4; ++sm) {
            #pragma unroll
            for (int tn = 0; tn < 2; ++tn) {
                #pragma unroll
                for (int r = 0; r < 4; ++r)
                    sc[sm][tn][r] = __builtin_amdgcn_exp2f(sc[sm][tn][r] * C_EXP);
                accl[tn] += sc[sm][tn];
                bf16x4 pv = __builtin_convertvector(sc[sm][tn], bf16x4);
                *(bf16x4*)&Pl[w][(tn * 16 + c) * 72 + sm * 16 + g * 4] = pv;
            }
        }
        asm volatile("s_waitcnt lgkmcnt(0)" ::: "memory");

        // PV: O^T[v][t] += V^T-frag . P-frag
        bf16x8 vf[4][2], pa[2][2];
        #pragma unroll
        for (int vm = 0; vm < 4; ++vm)
            #pragma unroll
            for (int ks = 0; ks < 2; ++ks)
                vf[vm][ks] = *(const bf16x8*)&Vt[(vm * 16 + c) * 72 + ks * 32 + g * 8];
        #pragma unroll
        for (int tn = 0; tn < 2; ++tn)
            #pragma unroll
            for (int ks = 0; ks < 2; ++ks)
                pa[tn][ks] = *(const bf16x8*)&Pl[w][(tn * 16 + c) * 72 + ks * 32 + g * 8];
        #pragma unroll
        for (int vm = 0; vm < 4; ++vm)
            #pragma unroll
            for (int tn = 0; tn < 2; ++tn)
                #pragma unroll
                for (int ks = 0; ks < 2; ++ks)
                    o[vm][tn] = __builtin_amdgcn_mfma_f32_16x16x32_bf16(vf[vm][ks], pa[tn][ks], o[vm][tn], 0, 0, 0);

        __syncthreads();
    }

    // finish denominator: horizontal over 4 regs, then across g-groups (xor 16, 32)
    float inv[2];
    #pragma unroll
    for (int tn = 0; tn < 2; ++tn) {
        float s = (accl[tn][0] + accl[tn][1]) + (accl[tn][2] + accl[tn][3]);
        s += __shfl_xor(s, 16);
        s += __shfl_xor(s, 32);
        inv[tn] = 1.0f / s;
    }

    // epilogue: attnb[(b*2048+t)*1024 + h*64 + v] = O^T[v][t] * inv
    #pragma unroll
    for (int vm = 0; vm < 4; ++vm)
        #pragma unroll
        for (int tn = 0; tn < 2; ++tn) {
            const int t = twave + tn * 16 + c;
            f32x4 v4;
            #pragma unroll
            for (int r = 0; r < 4; ++r) v4[r] = o[vm][tn][r] * inv[tn];
            bf16x4 pv = __builtin_convertvector(v4, bf16x4);
            *(bf16x4*)(attnb + (size_t)(b * 2048 + t) * 1024 + h * 64 + vm * 16 + g * 4) = pv;
        }
}

// ---------------------------------------------------------------------------
extern "C" void kernel_launch(void* const* d_in, const int* in_sizes, int n_in,
                              void* d_out, int out_size, void* d_ws, size_t ws_size,
                              hipStream_t stream) {
    const float* query = (const float*)d_in[0];
    const float* value = (const float*)d_in[1];
    const int*   mask  = (const int*)d_in[2];
    const float* Wq = (const float*)d_in[3];
    const float* bq = (const float*)d_in[4];
    const float* Wk = (const float*)d_in[5];
    const float* bk = (const float*)d_in[6];
    const float* Wv = (const float*)d_in[7];
    const float* bv = (const float*)d_in[8];
    const float* Wo = (const float*)d_in[9];
    const float* bo = (const float*)d_in[10];

    char* ws = (char*)d_ws;
    unsigned short* WqT   = (unsigned short*)(ws + ((size_t)0  << 20));  // 2 MB
    unsigned short* WkT   = (unsigned short*)(ws + ((size_t)2  << 20));  // 2 MB
    unsigned short* WvT   = (unsigned short*)(ws + ((size_t)4  << 20));  // 2 MB
    unsigned short* WoT   = (unsigned short*)(ws + ((size_t)6  << 20));  // 2 MB
    unsigned short* Qp    = (unsigned short*)(ws + ((size_t)8  << 20));  // 16 MB
    unsigned short* Kp    = (unsigned short*)(ws + ((size_t)24 << 20));  // 16 MB
    unsigned short* VTp   = (unsigned short*)(ws + ((size_t)40 << 20));  // 16 MB ([bh][v][s])
    unsigned short* attnb = (unsigned short*)(ws + ((size_t)56 << 20));  // 16 MB
    unsigned char*  flags = (unsigned char*) (ws + ((size_t)72 << 20));  // 2048 B

    dim3 tg(16, 16);
    wtrans_kernel<<<tg, 256, 0, stream>>>(Wq, WqT);
    wtrans_kernel<<<tg, 256, 0, stream>>>(Wk, WkT);
    wtrans_kernel<<<tg, 256, 0, stream>>>(Wv, WvT);
    wtrans_kernel<<<tg, 256, 0, stream>>>(Wo, WoT);
    maskflag_kernel<<<2048, 256, 0, stream>>>(mask, flags);

    dim3 gp(8, 64);
    proj_gemm_kernel<0><<<gp, 256, 0, stream>>>(query, WqT, bq, Qp);
    proj_gemm_kernel<0><<<gp, 256, 0, stream>>>(value, WkT, bk, Kp);
    proj_gemm_kernel<1><<<gp, 256, 0, stream>>>(value, WvT, bv, VTp);

    dim3 ga(16, 64);
    attn_kernel<<<ga, 256, 0, stream>>>(Qp, Kp, VTp, mask, flags, attnb);

    final_gemm_kernel<<<gp, 256, 0, stream>>>(attnb, WoT, bo, (float*)d_out);
}

// Round 4
// 304.045 us; speedup vs baseline: 1.4552x; 1.0195x over previous
//
#include <hip/hip_runtime.h>

typedef __bf16 bf16x8 __attribute__((ext_vector_type(8)));
typedef __bf16 bf16x4 __attribute__((ext_vector_type(4)));
typedef float  f32x4  __attribute__((ext_vector_type(4)));
typedef int    i32x4  __attribute__((ext_vector_type(4)));

typedef __attribute__((address_space(1))) unsigned int as1_u32;
typedef __attribute__((address_space(3))) unsigned int as3_u32;

#define DEVI __device__ __forceinline__

DEVI unsigned short f2bf(float f) {
    union { float f; unsigned u; } v; v.f = f;
    unsigned r = (v.u + 0x7fffu + ((v.u >> 16) & 1u)) >> 16;
    return (unsigned short)r;
}

// direct global->LDS 16B: lane L's 16B lands at ldsbase + L*16
DEVI void gload16(const void* g, void* l) {
    __builtin_amdgcn_global_load_lds((const as1_u32*)g, (as3_u32*)l, 16, 0, 0);
}

// softmax(x/8) = exp2(x * 0.125 * log2(e)); scale folded into Q projection.
#define C_EXP 0.18033688011112042f
// -10000 * log2(e)
#define MASK_ADD (-14426.950408889634f)

// ---------------------------------------------------------------------------
// Transpose 1024x1024 f32 -> bf16 (optionally scaled): WT[n][k] = W[k][n]*scale
// ---------------------------------------------------------------------------
__global__ __launch_bounds__(256) void wtrans_kernel(const float* __restrict__ W,
                                                     unsigned short* __restrict__ WT,
                                                     float scale) {
    __shared__ float tile[64][65];
    const int k0 = blockIdx.x * 64, n0 = blockIdx.y * 64;
    const int i = threadIdx.x;
    const int c4 = (i & 15) * 4, rbase = i >> 4;
    for (int rr = 0; rr < 4; ++rr) {
        const int kl = rbase + rr * 16;
        const float4 v = *(const float4*)(W + (size_t)(k0 + kl) * 1024 + n0 + c4);
        tile[kl][c4 + 0] = v.x; tile[kl][c4 + 1] = v.y;
        tile[kl][c4 + 2] = v.z; tile[kl][c4 + 3] = v.w;
    }
    __syncthreads();
    for (int rr = 0; rr < 4; ++rr) {
        const int nl = rbase + rr * 16;
        ushort4 o;
        o.x = f2bf(tile[c4 + 0][nl] * scale); o.y = f2bf(tile[c4 + 1][nl] * scale);
        o.z = f2bf(tile[c4 + 2][nl] * scale); o.w = f2bf(tile[c4 + 3][nl] * scale);
        *(ushort4*)(WT + (size_t)(n0 + nl) * 1024 + k0 + c4) = o;
    }
}

// ---------------------------------------------------------------------------
// Mask all-true flags per (b, 128-row t-tile, 64-col s-tile). mask is int32.
// ---------------------------------------------------------------------------
__global__ __launch_bounds__(256) void maskflag_kernel(const int* __restrict__ mask,
                                                       unsigned char* __restrict__ flags) {
    const int bid = blockIdx.x;
    const int b = bid >> 9, rem = bid & 511;
    const int tb = rem >> 5, si = rem & 31;
    const int i = threadIdx.x;
    const int t = tb * 128 + (i >> 1);
    const int s = si * 64 + (i & 1) * 32;
    const uint4* p = (const uint4*)(mask + ((size_t)(b * 2048 + t)) * 2048 + s);
    int ok = 1;
    #pragma unroll
    for (int u = 0; u < 8; ++u) {
        const uint4 a = p[u];
        ok &= (a.x != 0) & (a.y != 0) & (a.z != 0) & (a.w != 0);
    }
    int all = __syncthreads_and(ok);
    if (i == 0) flags[bid] = (unsigned char)all;
}

// ---------------------------------------------------------------------------
// Projection GEMM: C[m,n] = A_f32[m,:] . WT_bf16[n,:] + bias[n]*bscale
// VT_MODE=0: write bf16 to [b][h][t][c]   (Q, K layout)
// VT_MODE=1: write bf16 to [b][h][c][t]   (V^T layout, for attn PV)
// ---------------------------------------------------------------------------
template <int VT_MODE>
__global__ __launch_bounds__(256) void proj_gemm_kernel(const float* __restrict__ A,
                                                        const unsigned short* __restrict__ BT,
                                                        const float* __restrict__ bias,
                                                        float bscale,
                                                        unsigned short* __restrict__ O) {
    __shared__ __align__(16) unsigned short Ab[128 * 72];
    __shared__ __align__(16) unsigned short Bb[128 * 72];
    const int n0 = blockIdx.x * 128, m0 = blockIdx.y * 128;
    const int i = threadIdx.x, w = i >> 6, l = i & 63;
    const int wm = w >> 1, wn = w & 1;
    const int lrow = l & 15, lhi = l >> 4;
    const int arow = i >> 1, kseg = (i & 1) * 16;

    f32x4 acc[4][4] = {};

    for (int k0 = 0; k0 < 1024; k0 += 32) {
        {
            const float* src = A + (size_t)(m0 + arow) * 1024 + k0 + kseg;
            const float4 v0 = *(const float4*)(src);
            const float4 v1 = *(const float4*)(src + 4);
            const float4 v2 = *(const float4*)(src + 8);
            const float4 v3 = *(const float4*)(src + 12);
            i32x4 w0, w1;
            w0[0] = (int)(f2bf(v0.x) | ((unsigned)f2bf(v0.y) << 16));
            w0[1] = (int)(f2bf(v0.z) | ((unsigned)f2bf(v0.w) << 16));
            w0[2] = (int)(f2bf(v1.x) | ((unsigned)f2bf(v1.y) << 16));
            w0[3] = (int)(f2bf(v1.z) | ((unsigned)f2bf(v1.w) << 16));
            w1[0] = (int)(f2bf(v2.x) | ((unsigned)f2bf(v2.y) << 16));
            w1[1] = (int)(f2bf(v2.z) | ((unsigned)f2bf(v2.w) << 16));
            w1[2] = (int)(f2bf(v3.x) | ((unsigned)f2bf(v3.y) << 16));
            w1[3] = (int)(f2bf(v3.z) | ((unsigned)f2bf(v3.w) << 16));
            *(i32x4*)&Ab[arow * 72 + kseg]     = w0;
            *(i32x4*)&Ab[arow * 72 + kseg + 8] = w1;
        }
        {
            const unsigned short* src = BT + (size_t)(n0 + arow) * 1024 + k0 + kseg;
            const i32x4 v0 = *(const i32x4*)(src);
            const i32x4 v1 = *(const i32x4*)(src + 8);
            *(i32x4*)&Bb[arow * 72 + kseg]     = v0;
            *(i32x4*)&Bb[arow * 72 + kseg + 8] = v1;
        }
        __syncthreads();
        bf16x8 af[4], bfr[4];
        #pragma unroll
        for (int mf = 0; mf < 4; ++mf)
            af[mf] = *(const bf16x8*)&Ab[(wm * 64 + mf * 16 + lrow) * 72 + lhi * 8];
        #pragma unroll
        for (int nf = 0; nf < 4; ++nf)
            bfr[nf] = *(const bf16x8*)&Bb[(wn * 64 + nf * 16 + lrow) * 72 + lhi * 8];
        #pragma unroll
        for (int mf = 0; mf < 4; ++mf)
            #pragma unroll
            for (int nf = 0; nf < 4; ++nf)
                acc[mf][nf] = __builtin_amdgcn_mfma_f32_16x16x32_bf16(af[mf], bfr[nf], acc[mf][nf], 0, 0, 0);
        __syncthreads();
    }

    #pragma unroll
    for (int nf = 0; nf < 4; ++nf) {
        const int n = n0 + wn * 64 + nf * 16 + lrow;
        const float bv = bias[n] * bscale;
        const int h = n >> 6, c = n & 63;
        #pragma unroll
        for (int mf = 0; mf < 4; ++mf) {
            const int mbase = m0 + wm * 64 + mf * 16 + lhi * 4;
            const int b = mbase >> 11, t = mbase & 2047;
            if (VT_MODE == 0) {
                #pragma unroll
                for (int r = 0; r < 4; ++r)
                    O[(((size_t)(b * 16 + h)) * 2048 + t + r) * 64 + c] = f2bf(acc[mf][nf][r] + bv);
            } else {
                f32x4 v;
                #pragma unroll
                for (int r = 0; r < 4; ++r) v[r] = acc[mf][nf][r] + bv;
                bf16x4 pv = __builtin_convertvector(v, bf16x4);
                *(bf16x4*)(O + (((size_t)(b * 16 + h)) * 64 + c) * 2048 + t) = pv;
            }
        }
    }
}

// ---------------------------------------------------------------------------
// Final GEMM: out[m,n] = attn_bf16[m,:] . WoT_bf16[n,:] + bo[n]   (f32 out)
// ---------------------------------------------------------------------------
__global__ __launch_bounds__(256) void final_gemm_kernel(const unsigned short* __restrict__ A,
                                                         const unsigned short* __restrict__ BT,
                                                         const float* __restrict__ bias,
                                                         float* __restrict__ O) {
    __shared__ __align__(16) unsigned short Ab[128 * 72];
    __shared__ __align__(16) unsigned short Bb[128 * 72];
    const int n0 = blockIdx.x * 128, m0 = blockIdx.y * 128;
    const int i = threadIdx.x, w = i >> 6, l = i & 63;
    const int wm = w >> 1, wn = w & 1;
    const int lrow = l & 15, lhi = l >> 4;
    const int arow = i >> 1, kseg = (i & 1) * 16;

    f32x4 acc[4][4] = {};

    for (int k0 = 0; k0 < 1024; k0 += 32) {
        {
            const unsigned short* src = A + (size_t)(m0 + arow) * 1024 + k0 + kseg;
            const i32x4 v0 = *(const i32x4*)(src);
            const i32x4 v1 = *(const i32x4*)(src + 8);
            *(i32x4*)&Ab[arow * 72 + kseg]     = v0;
            *(i32x4*)&Ab[arow * 72 + kseg + 8] = v1;
        }
        {
            const unsigned short* src = BT + (size_t)(n0 + arow) * 1024 + k0 + kseg;
            const i32x4 v0 = *(const i32x4*)(src);
            const i32x4 v1 = *(const i32x4*)(src + 8);
            *(i32x4*)&Bb[arow * 72 + kseg]     = v0;
            *(i32x4*)&Bb[arow * 72 + kseg + 8] = v1;
        }
        __syncthreads();
        bf16x8 af[4], bfr[4];
        #pragma unroll
        for (int mf = 0; mf < 4; ++mf)
            af[mf] = *(const bf16x8*)&Ab[(wm * 64 + mf * 16 + lrow) * 72 + lhi * 8];
        #pragma unroll
        for (int nf = 0; nf < 4; ++nf)
            bfr[nf] = *(const bf16x8*)&Bb[(wn * 64 + nf * 16 + lrow) * 72 + lhi * 8];
        #pragma unroll
        for (int mf = 0; mf < 4; ++mf)
            #pragma unroll
            for (int nf = 0; nf < 4; ++nf)
                acc[mf][nf] = __builtin_amdgcn_mfma_f32_16x16x32_bf16(af[mf], bfr[nf], acc[mf][nf], 0, 0, 0);
        __syncthreads();
    }

    #pragma unroll
    for (int nf = 0; nf < 4; ++nf) {
        const int n = n0 + wn * 64 + nf * 16 + lrow;
        const float bv = bias[n];
        #pragma unroll
        for (int mf = 0; mf < 4; ++mf) {
            #pragma unroll
            for (int r = 0; r < 4; ++r) {
                const int m = m0 + wm * 64 + mf * 16 + lhi * 4 + r;
                O[(size_t)m * 1024 + n] = acc[mf][nf][r] + bv;
            }
        }
    }
}

// ---------------------------------------------------------------------------
// Flash attention, swapped QK^T, no running max (scores pre-scaled, bounded).
// grid = (16, 64), 256 threads (4 waves), wave owns 32 Q rows.
// Q (pre-scaled by C_EXP), K: bf16 [bh][2048][64]; V^T: bf16 [bh][64][2048].
// K/V tiles staged via global_load_lds (pre-swizzled source, swizzled reads),
// double-buffered 2-phase pipeline. Denominator accumulated via ones-MFMA.
// ---------------------------------------------------------------------------
__global__ __launch_bounds__(256) void attn_kernel(const unsigned short* __restrict__ Qp,
                                                   const unsigned short* __restrict__ Kp,
                                                   const unsigned short* __restrict__ VTp,
                                                   const int* __restrict__ mask,
                                                   const unsigned char* __restrict__ flags,
                                                   unsigned short* __restrict__ attnb) {
    __shared__ __align__(16) unsigned short Kt[2][64 * 64];  // linear, XOR-swizzled content
    __shared__ __align__(16) unsigned short Vt[2][64 * 64];
    __shared__ __align__(16) unsigned short Pl[4][32 * 72];  // per-wave [t][s], stride 72

    const int tb = blockIdx.x;
    const int bh = blockIdx.y;
    const int b = bh >> 4, h = bh & 15;
    const int i = threadIdx.x, w = i >> 6, l = i & 63;
    const int c = l & 15, g = l >> 4;
    const int cs = (c & 7) * 8;              // read-side swizzle (elems)

    const unsigned short* Qb  = Qp  + (size_t)bh * 2048 * 64;
    const unsigned short* Kb  = Kp  + (size_t)bh * 2048 * 64;
    const unsigned short* VTb = VTp + (size_t)bh * 64 * 2048;

    const int twave = tb * 128 + w * 32;

    // Q as B-operand: lane holds Q[t = twave + tn*16 + c][dk = ks*32 + g*8 + j]
    bf16x8 qf[2][2];
    #pragma unroll
    for (int tn = 0; tn < 2; ++tn)
        #pragma unroll
        for (int ks = 0; ks < 2; ++ks)
            qf[tn][ks] = *(const bf16x8*)(Qb + (size_t)(twave + tn * 16 + c) * 64 + ks * 32 + g * 8);

    f32x4 o[4][2] = {};     // O^T accum: v = vm*16+g*4+r, t = twave+tn*16+c
    f32x4 dacc[2] = {};     // softmax denominator via ones-MFMA (per tn)

    bf16x8 onesf;
    #pragma unroll
    for (int j = 0; j < 8; ++j) onesf[j] = (__bf16)1.0f;

    // staging geometry: wave stages 16 rows (2 instrs x 8 rows), lane L:
    // LDS slot (row = base + L>>3, L&7) gets global chunk (row, (L&7)^(L>>3))
    const int r8 = l >> 3;
    const int sl8 = (l & 7) ^ r8;
    const int rwb = w * 16;

    // prologue: stage tile 0 into buffer 0
    #pragma unroll
    for (int u = 0; u < 2; ++u) {
        const int row = rwb + u * 8;
        gload16(Kb + (size_t)(row + r8) * 64 + sl8 * 8, &Kt[0][row * 64]);
        gload16(VTb + (size_t)(row + r8) * 2048 + sl8 * 8, &Vt[0][row * 64]);
    }
    __syncthreads();

    for (int it = 0; it < 32; ++it) {
        const int buf = it & 1;
        const int s0 = it * 64;

        // issue next-tile stage before compute (2-phase pipeline)
        if (it < 31) {
            const int s0n = s0 + 64;
            #pragma unroll
            for (int u = 0; u < 2; ++u) {
                const int row = rwb + u * 8;
                gload16(Kb + (size_t)(s0n + row + r8) * 64 + sl8 * 8, &Kt[buf ^ 1][row * 64]);
                gload16(VTb + (size_t)(row + r8) * 2048 + s0n + sl8 * 8, &Vt[buf ^ 1][row * 64]);
            }
        }

        // QK^T swapped: sc[sm][tn], lane: s = sm*16+g*4+r, t = twave+tn*16+c
        f32x4 sc[4][2] = {};
        #pragma unroll
        for (int sm = 0; sm < 4; ++sm)
            #pragma unroll
            for (int ks = 0; ks < 2; ++ks) {
                const bf16x8 kf = *(const bf16x8*)&Kt[buf][(sm * 16 + c) * 64 + ((ks * 32 + g * 8) ^ cs)];
                #pragma unroll
                for (int tn = 0; tn < 2; ++tn)
                    sc[sm][tn] = __builtin_amdgcn_mfma_f32_16x16x32_bf16(kf, qf[tn][ks], sc[sm][tn], 0, 0, 0);
            }

        // mask fallback (scores are in exp2 domain: adder = -10000*log2e)
        const int flg = flags[(b * 16 + tb) * 32 + it];
        if (!flg) {
            #pragma unroll
            for (int sm = 0; sm < 4; ++sm)
                #pragma unroll
                for (int tn = 0; tn < 2; ++tn)
                    #pragma unroll
                    for (int r = 0; r < 4; ++r) {
                        const int t = twave + tn * 16 + c;
                        const int s = s0 + sm * 16 + g * 4 + r;
                        if (mask[(size_t)(b * 2048 + t) * 2048 + s] == 0) sc[sm][tn][r] += MASK_ADD;
                    }
        }

        // p = exp2(sc) (scale pre-folded into Q); write P bf16 to per-wave LDS
        #pragma unroll
        for (int sm = 0; sm < 4; ++sm)
            #pragma unroll
            for (int tn = 0; tn < 2; ++tn) {
                f32x4 p;
                #pragma unroll
                for (int r = 0; r < 4; ++r)
                    p[r] = __builtin_amdgcn_exp2f(sc[sm][tn][r]);
                bf16x4 pv = __builtin_convertvector(p, bf16x4);
                *(bf16x4*)&Pl[w][(tn * 16 + c) * 72 + sm * 16 + g * 4] = pv;
            }
        asm volatile("s_waitcnt lgkmcnt(0)" ::: "memory");

        // PV + denominator
        bf16x8 vf[4][2], pa[2][2];
        #pragma unroll
        for (int vm = 0; vm < 4; ++vm)
            #pragma unroll
            for (int ks = 0; ks < 2; ++ks)
                vf[vm][ks] = *(const bf16x8*)&Vt[buf][(vm * 16 + c) * 64 + ((ks * 32 + g * 8) ^ cs)];
        #pragma unroll
        for (int tn = 0; tn < 2; ++tn)
            #pragma unroll
            for (int ks = 0; ks < 2; ++ks)
                pa[tn][ks] = *(const bf16x8*)&Pl[w][(tn * 16 + c) * 72 + ks * 32 + g * 8];
        #pragma unroll
        for (int tn = 0; tn < 2; ++tn)
            #pragma unroll
            for (int ks = 0; ks < 2; ++ks)
                dacc[tn] = __builtin_amdgcn_mfma_f32_16x16x32_bf16(onesf, pa[tn][ks], dacc[tn], 0, 0, 0);
        #pragma unroll
        for (int vm = 0; vm < 4; ++vm)
            #pragma unroll
            for (int tn = 0; tn < 2; ++tn)
                #pragma unroll
                for (int ks = 0; ks < 2; ++ks)
                    o[vm][tn] = __builtin_amdgcn_mfma_f32_16x16x32_bf16(vf[vm][ks], pa[tn][ks], o[vm][tn], 0, 0, 0);

        __syncthreads();  // drains vmcnt (stage loads) + lgkm, then barrier
    }

    // all lanes hold the full row denominator in every dacc[tn][r]
    float inv[2];
    #pragma unroll
    for (int tn = 0; tn < 2; ++tn) inv[tn] = 1.0f / dacc[tn][0];

    // epilogue: attnb[(b*2048+t)*1024 + h*64 + v] = O^T[v][t] * inv
    #pragma unroll
    for (int vm = 0; vm < 4; ++vm)
        #pragma unroll
        for (int tn = 0; tn < 2; ++tn) {
            const int t = twave + tn * 16 + c;
            f32x4 v4;
            #pragma unroll
            for (int r = 0; r < 4; ++r) v4[r] = o[vm][tn][r] * inv[tn];
            bf16x4 pv = __builtin_convertvector(v4, bf16x4);
            *(bf16x4*)(attnb + (size_t)(b * 2048 + t) * 1024 + h * 64 + vm * 16 + g * 4) = pv;
        }
}

// ---------------------------------------------------------------------------
extern "C" void kernel_launch(void* const* d_in, const int* in_sizes, int n_in,
                              void* d_out, int out_size, void* d_ws, size_t ws_size,
                              hipStream_t stream) {
    const float* query = (const float*)d_in[0];
    const float* value = (const float*)d_in[1];
    const int*   mask  = (const int*)d_in[2];
    const float* Wq = (const float*)d_in[3];
    const float* bq = (const float*)d_in[4];
    const float* Wk = (const float*)d_in[5];
    const float* bk = (const float*)d_in[6];
    const float* Wv = (const float*)d_in[7];
    const float* bv = (const float*)d_in[8];
    const float* Wo = (const float*)d_in[9];
    const float* bo = (const float*)d_in[10];

    char* ws = (char*)d_ws;
    unsigned short* WqT   = (unsigned short*)(ws + ((size_t)0  << 20));  // 2 MB (scaled by C_EXP)
    unsigned short* WkT   = (unsigned short*)(ws + ((size_t)2  << 20));  // 2 MB
    unsigned short* WvT   = (unsigned short*)(ws + ((size_t)4  << 20));  // 2 MB
    unsigned short* WoT   = (unsigned short*)(ws + ((size_t)6  << 20));  // 2 MB
    unsigned short* Qp    = (unsigned short*)(ws + ((size_t)8  << 20));  // 16 MB (pre-scaled Q)
    unsigned short* Kp    = (unsigned short*)(ws + ((size_t)24 << 20));  // 16 MB
    unsigned short* VTp   = (unsigned short*)(ws + ((size_t)40 << 20));  // 16 MB ([bh][v][s])
    unsigned short* attnb = (unsigned short*)(ws + ((size_t)56 << 20));  // 16 MB
    unsigned char*  flags = (unsigned char*) (ws + ((size_t)72 << 20));  // 2048 B

    dim3 tg(16, 16);
    wtrans_kernel<<<tg, 256, 0, stream>>>(Wq, WqT, C_EXP);
    wtrans_kernel<<<tg, 256, 0, stream>>>(Wk, WkT, 1.0f);
    wtrans_kernel<<<tg, 256, 0, stream>>>(Wv, WvT, 1.0f);
    wtrans_kernel<<<tg, 256, 0, stream>>>(Wo, WoT, 1.0f);
    maskflag_kernel<<<2048, 256, 0, stream>>>(mask, flags);

    dim3 gp(8, 64);
    proj_gemm_kernel<0><<<gp, 256, 0, stream>>>(query, WqT, bq, C_EXP, Qp);
    proj_gemm_kernel<0><<<gp, 256, 0, stream>>>(value, WkT, bk, 1.0f, Kp);
    proj_gemm_kernel<1><<<gp, 256, 0, stream>>>(value, WvT, bv, 1.0f, VTp);

    dim3 ga(16, 64);
    attn_kernel<<<ga, 256, 0, stream>>>(Qp, Kp, VTp, mask, flags, attnb);

    final_gemm_kernel<<<gp, 256, 0, stream>>>(attnb, WoT, bo, (float*)d_out);
}

// Round 5
// 271.669 us; speedup vs baseline: 1.6286x; 1.1192x over previous
//
#include <hip/hip_runtime.h>

typedef __bf16 bf16x8 __attribute__((ext_vector_type(8)));
typedef __bf16 bf16x4 __attribute__((ext_vector_type(4)));
typedef float  f32x4  __attribute__((ext_vector_type(4)));
typedef int    i32x4  __attribute__((ext_vector_type(4)));
typedef short  s16x4  __attribute__((ext_vector_type(4)));

typedef __attribute__((address_space(1))) unsigned int as1_u32;
typedef __attribute__((address_space(3))) unsigned int as3_u32;

#define DEVI __device__ __forceinline__

DEVI unsigned short f2bf(float f) {
    union { float f; unsigned u; } v; v.f = f;
    unsigned r = (v.u + 0x7fffu + ((v.u >> 16) & 1u)) >> 16;
    return (unsigned short)r;
}

// direct global->LDS 16B: lane L's 16B lands at ldsbase + L*16
DEVI void gload16(const void* g, void* l) {
    __builtin_amdgcn_global_load_lds((const as1_u32*)g, (as3_u32*)l, 16, 0, 0);
}

// K=16 bf16 MFMA (A,B = 4 bf16 in a VGPR pair)
#if __has_builtin(__builtin_amdgcn_mfma_f32_16x16x16bf16_1k)
DEVI f32x4 mfma16(s16x4 a, s16x4 b, f32x4 c) {
    return __builtin_amdgcn_mfma_f32_16x16x16bf16_1k(a, b, c, 0, 0, 0);
}
#else
DEVI f32x4 mfma16(s16x4 a, s16x4 b, f32x4 c) {
    asm("v_mfma_f32_16x16x16_bf16 %0, %1, %2, %0" : "+v"(c) : "v"(a), "v"(b));
    return c;
}
#endif

// softmax(x/8) = exp2(x * 0.125 * log2(e)); scale folded into Q projection.
#define C_EXP 0.18033688011112042f
// -10000 * log2(e)
#define MASK_ADD (-14426.950408889634f)

// ---------------------------------------------------------------------------
// f32 -> bf16 bulk convert (n8 = elements/8)
// ---------------------------------------------------------------------------
__global__ __launch_bounds__(256) void cvt_kernel(const float* __restrict__ in,
                                                  unsigned short* __restrict__ out,
                                                  int n8) {
    const int stride = gridDim.x * 256;
    for (int idx = blockIdx.x * 256 + threadIdx.x; idx < n8; idx += stride) {
        const f32x4 a = *(const f32x4*)(in + (size_t)idx * 8);
        const f32x4 b = *(const f32x4*)(in + (size_t)idx * 8 + 4);
        union { bf16x4 v[2]; i32x4 q; } u;
        u.v[0] = __builtin_convertvector(a, bf16x4);
        u.v[1] = __builtin_convertvector(b, bf16x4);
        *(i32x4*)(out + (size_t)idx * 8) = u.q;
    }
}

// ---------------------------------------------------------------------------
// Transpose 4x (1024x1024) f32 -> bf16: WT[n][k] = W[k][n]*scale, z selects.
// ---------------------------------------------------------------------------
__global__ __launch_bounds__(256) void wtrans_kernel(const float* __restrict__ W0,
                                                     const float* __restrict__ W1,
                                                     const float* __restrict__ W2,
                                                     const float* __restrict__ W3,
                                                     unsigned short* __restrict__ T0,
                                                     unsigned short* __restrict__ T1,
                                                     unsigned short* __restrict__ T2,
                                                     unsigned short* __restrict__ T3) {
    __shared__ float tile[64][65];
    const float* W;
    unsigned short* WT;
    float scale = 1.0f;
    switch (blockIdx.z) {
        case 0:  W = W0; WT = T0; scale = C_EXP; break;
        case 1:  W = W1; WT = T1; break;
        case 2:  W = W2; WT = T2; break;
        default: W = W3; WT = T3; break;
    }
    const int k0 = blockIdx.x * 64, n0 = blockIdx.y * 64;
    const int i = threadIdx.x;
    const int c4 = (i & 15) * 4, rbase = i >> 4;
    for (int rr = 0; rr < 4; ++rr) {
        const int kl = rbase + rr * 16;
        const float4 v = *(const float4*)(W + (size_t)(k0 + kl) * 1024 + n0 + c4);
        tile[kl][c4 + 0] = v.x; tile[kl][c4 + 1] = v.y;
        tile[kl][c4 + 2] = v.z; tile[kl][c4 + 3] = v.w;
    }
    __syncthreads();
    for (int rr = 0; rr < 4; ++rr) {
        const int nl = rbase + rr * 16;
        ushort4 o;
        o.x = f2bf(tile[c4 + 0][nl] * scale); o.y = f2bf(tile[c4 + 1][nl] * scale);
        o.z = f2bf(tile[c4 + 2][nl] * scale); o.w = f2bf(tile[c4 + 3][nl] * scale);
        *(ushort4*)(WT + (size_t)(n0 + nl) * 1024 + k0 + c4) = o;
    }
}

// ---------------------------------------------------------------------------
// Mask all-true flags per (b, 128-row t-tile, 64-col s-tile). mask is int32.
// ---------------------------------------------------------------------------
__global__ __launch_bounds__(256) void maskflag_kernel(const int* __restrict__ mask,
                                                       unsigned char* __restrict__ flags) {
    const int bid = blockIdx.x;
    const int b = bid >> 9, rem = bid & 511;
    const int tb = rem >> 5, si = rem & 31;
    const int i = threadIdx.x;
    const int t = tb * 128 + (i >> 1);
    const int s = si * 64 + (i & 1) * 32;
    const uint4* p = (const uint4*)(mask + ((size_t)(b * 2048 + t)) * 2048 + s);
    int ok = 1;
    #pragma unroll
    for (int u = 0; u < 8; ++u) {
        const uint4 a = p[u];
        ok &= (a.x != 0) & (a.y != 0) & (a.z != 0) & (a.w != 0);
    }
    int all = __syncthreads_and(ok);
    if (i == 0) flags[bid] = (unsigned char)all;
}

// ---------------------------------------------------------------------------
// Unified bf16 GEMM, m97-style: C[m,n] = A[m,:] . BT[n,:] + bias[n]*bscale
// A [M][1024] bf16, BT [1024][1024] bf16. 128x128 tile, BK=32, 4 waves,
// global_load_lds w16 staging, linear LDS + chunk swizzle.
// MODE 0: bf16 scatter [b][h][t][c];  MODE 1: bf16 V^T [b][h][c][t];
// MODE 2: f32 linear [m][n].
// ---------------------------------------------------------------------------
template <int MODE>
__global__ __launch_bounds__(256) void mm_kernel(const unsigned short* __restrict__ A,
                                                 const unsigned short* __restrict__ BT,
                                                 const float* __restrict__ bias,
                                                 float bscale,
                                                 void* __restrict__ Ov) {
    __shared__ __align__(16) unsigned short Ab[128 * 32];
    __shared__ __align__(16) unsigned short Bb[128 * 32];
    const int n0 = blockIdx.x * 128, m0 = blockIdx.y * 128;
    const int i = threadIdx.x, w = i >> 6, l = i & 63;
    const int wm = w >> 1, wn = w & 1;
    const int c = l & 15, g = l >> 4;
    // staging: lane L covers (row = base + L>>2, slot = L&3); source chunk
    // = (L&3)^((L>>3)&3), so LDS slot s holds global chunk s ^ ((row>>1)&3).
    const int rloc = l >> 2;
    const int schunk = ((l & 3) ^ ((l >> 3) & 3)) * 8;
    const int rs = (c >> 1) & 3;

    f32x4 acc[4][4] = {};

    const unsigned short* Asrc = A + (size_t)(m0 + w * 32 + rloc) * 1024 + schunk;
    const unsigned short* Bsrc = BT + (size_t)(n0 + w * 32 + rloc) * 1024 + schunk;
    unsigned short* AbBase = &Ab[(w * 32) * 32];
    unsigned short* BbBase = &Bb[(w * 32) * 32];

    for (int k0 = 0; k0 < 1024; k0 += 32) {
        gload16(Asrc + k0,             AbBase);
        gload16(Asrc + k0 + 16 * 1024, AbBase + 16 * 32);
        gload16(Bsrc + k0,             BbBase);
        gload16(Bsrc + k0 + 16 * 1024, BbBase + 16 * 32);
        __syncthreads();
        bf16x8 af[4], bfr[4];
        #pragma unroll
        for (int mf = 0; mf < 4; ++mf)
            af[mf] = *(const bf16x8*)&Ab[(wm * 64 + mf * 16 + c) * 32 + (g ^ rs) * 8];
        #pragma unroll
        for (int nf = 0; nf < 4; ++nf)
            bfr[nf] = *(const bf16x8*)&Bb[(wn * 64 + nf * 16 + c) * 32 + (g ^ rs) * 8];
        #pragma unroll
        for (int mf = 0; mf < 4; ++mf)
            #pragma unroll
            for (int nf = 0; nf < 4; ++nf)
                acc[mf][nf] = __builtin_amdgcn_mfma_f32_16x16x32_bf16(af[mf], bfr[nf], acc[mf][nf], 0, 0, 0);
        __syncthreads();
    }

    #pragma unroll
    for (int nf = 0; nf < 4; ++nf) {
        const int n = n0 + wn * 64 + nf * 16 + c;
        const float bv = bias[n] * bscale;
        const int h = n >> 6, cc = n & 63;
        #pragma unroll
        for (int mf = 0; mf < 4; ++mf) {
            const int mbase = m0 + wm * 64 + mf * 16 + g * 4;
            if (MODE == 0) {
                const int b = mbase >> 11, t = mbase & 2047;
                unsigned short* O = (unsigned short*)Ov;
                #pragma unroll
                for (int r = 0; r < 4; ++r)
                    O[(((size_t)(b * 16 + h)) * 2048 + t + r) * 64 + cc] = f2bf(acc[mf][nf][r] + bv);
            } else if (MODE == 1) {
                const int b = mbase >> 11, t = mbase & 2047;
                f32x4 v;
                #pragma unroll
                for (int r = 0; r < 4; ++r) v[r] = acc[mf][nf][r] + bv;
                bf16x4 pv = __builtin_convertvector(v, bf16x4);
                unsigned short* O = (unsigned short*)Ov;
                *(bf16x4*)(O + (((size_t)(b * 16 + h)) * 64 + cc) * 2048 + t) = pv;
            } else {
                float* O = (float*)Ov;
                #pragma unroll
                for (int r = 0; r < 4; ++r)
                    O[(size_t)(mbase + r) * 1024 + n] = acc[mf][nf][r] + bv;
            }
        }
    }
}

// ---------------------------------------------------------------------------
// Flash attention, swapped QK^T, P kept fully in registers:
// QK^T via 16x16x32 (S^T lane layout: s = sm*16+g*4+r, t = tn*16+c), then PV
// via 16x16x16 MFMA whose B-fragment k-granularity (4) matches the C-layout
// row granularity -> sc[sm][tn] IS the PV B-operand for k-chunk sm. No P LDS.
// K/V staged via global_load_lds (chunk-swizzled), double-buffered.
// Denominator via ones-MFMA (K16). grid = (16, 64), 4 waves.
// ---------------------------------------------------------------------------
__global__ __launch_bounds__(256) void attn_kernel(const unsigned short* __restrict__ Qp,
                                                   const unsigned short* __restrict__ Kp,
                                                   const unsigned short* __restrict__ VTp,
                                                   const int* __restrict__ mask,
                                                   const unsigned char* __restrict__ flags,
                                                   unsigned short* __restrict__ attnb) {
    __shared__ __align__(16) unsigned short Kt[2][64 * 64];  // [s][dk], swizzled chunks
    __shared__ __align__(16) unsigned short Vt[2][64 * 64];  // [v][s],  swizzled chunks

    const int tb = blockIdx.x;
    const int bh = blockIdx.y;
    const int b = bh >> 4, h = bh & 15;
    const int i = threadIdx.x, w = i >> 6, l = i & 63;
    const int c = l & 15, g = l >> 4;
    const int cs = (c & 7) * 8;              // read-side chunk swizzle (elems)

    const unsigned short* Qb  = Qp  + (size_t)bh * 2048 * 64;
    const unsigned short* Kb  = Kp  + (size_t)bh * 2048 * 64;
    const unsigned short* VTb = VTp + (size_t)bh * 64 * 2048;

    const int twave = tb * 128 + w * 32;

    // Q as B-operand (K32): lane holds Q[t = twave+tn*16+c][dk = ks*32+g*8+j]
    bf16x8 qf[2][2];
    #pragma unroll
    for (int tn = 0; tn < 2; ++tn)
        #pragma unroll
        for (int ks = 0; ks < 2; ++ks)
            qf[tn][ks] = *(const bf16x8*)(Qb + (size_t)(twave + tn * 16 + c) * 64 + ks * 32 + g * 8);

    f32x4 o[4][2] = {};     // O^T accum: v = vm*16+g*4+r, t = twave+tn*16+c
    f32x4 dacc[2] = {};     // denominator via ones-MFMA

    s16x4 ones;
    #pragma unroll
    for (int j = 0; j < 4; ++j) ones[j] = (short)0x3F80;  // bf16 1.0

    // staging: lane L -> LDS (row = rwb + u*8 + L>>3, slot L&7); source chunk
    // (L&7) ^ (L>>3)  => LDS slot s of row r holds global chunk s ^ (r&7).
    const int r8 = l >> 3;
    const int sl8 = (l & 7) ^ r8;
    const int rwb = w * 16;

    #pragma unroll
    for (int u = 0; u < 2; ++u) {
        const int row = rwb + u * 8;
        gload16(Kb + (size_t)(row + r8) * 64 + sl8 * 8, &Kt[0][row * 64]);
        gload16(VTb + (size_t)(row + r8) * 2048 + sl8 * 8, &Vt[0][row * 64]);
    }
    __syncthreads();

    for (int it = 0; it < 32; ++it) {
        const int buf = it & 1;
        const int s0 = it * 64;

        // issue next-tile stage (lands in buf^1; drained by end-of-iter barrier)
        if (it < 31) {
            const int s0n = s0 + 64;
            #pragma unroll
            for (int u = 0; u < 2; ++u) {
                const int row = rwb + u * 8;
                gload16(Kb + (size_t)(s0n + row + r8) * 64 + sl8 * 8, &Kt[buf ^ 1][row * 64]);
                gload16(VTb + (size_t)(row + r8) * 2048 + s0n + sl8 * 8, &Vt[buf ^ 1][row * 64]);
            }
        }

        // QK^T swapped (K32): sc[sm][tn], lane: s = s0+sm*16+g*4+r, t = twave+tn*16+c
        f32x4 sc[4][2] = {};
        #pragma unroll
        for (int sm = 0; sm < 4; ++sm)
            #pragma unroll
            for (int ks = 0; ks < 2; ++ks) {
                const bf16x8 kf = *(const bf16x8*)&Kt[buf][(sm * 16 + c) * 64 + ((ks * 32 + g * 8) ^ cs)];
                #pragma unroll
                for (int tn = 0; tn < 2; ++tn)
                    sc[sm][tn] = __builtin_amdgcn_mfma_f32_16x16x32_bf16(kf, qf[tn][ks], sc[sm][tn], 0, 0, 0);
            }

        // mask fallback (exp2 domain)
        const int flg = flags[(b * 16 + tb) * 32 + it];
        if (!flg) {
            #pragma unroll
            for (int sm = 0; sm < 4; ++sm)
                #pragma unroll
                for (int tn = 0; tn < 2; ++tn)
                    #pragma unroll
                    for (int r = 0; r < 4; ++r) {
                        const int t = twave + tn * 16 + c;
                        const int s = s0 + sm * 16 + g * 4 + r;
                        if (mask[(size_t)(b * 2048 + t) * 2048 + s] == 0) sc[sm][tn][r] += MASK_ADD;
                    }
        }

        // p = exp2(sc); pa[tn][kc] is directly the K16 B-fragment (k = g*4+j)
        s16x4 pa[2][4];
        #pragma unroll
        for (int sm = 0; sm < 4; ++sm)
            #pragma unroll
            for (int tn = 0; tn < 2; ++tn) {
                f32x4 p;
                #pragma unroll
                for (int r = 0; r < 4; ++r)
                    p[r] = __builtin_amdgcn_exp2f(sc[sm][tn][r]);
                union { bf16x4 bv; s16x4 sv; } u;
                u.bv = __builtin_convertvector(p, bf16x4);
                pa[tn][sm] = u.sv;
            }

        // denominator: dacc[tn] += ones . pa  (all rows equal row-sum of P^T col t)
        #pragma unroll
        for (int tn = 0; tn < 2; ++tn)
            #pragma unroll
            for (int kc = 0; kc < 4; ++kc)
                dacc[tn] = mfma16(ones, pa[tn][kc], dacc[tn]);

        // PV (K16): o[vm][tn] += V^T-frag(kc) . pa[tn][kc]
        #pragma unroll
        for (int vm = 0; vm < 4; ++vm) {
            #pragma unroll
            for (int kc = 0; kc < 4; ++kc) {
                const s16x4 vf = *(const s16x4*)&Vt[buf][(vm * 16 + c) * 64 +
                                  (((kc * 2 + (g >> 1)) ^ (c & 7)) * 8 + (g & 1) * 4)];
                #pragma unroll
                for (int tn = 0; tn < 2; ++tn)
                    o[vm][tn] = mfma16(vf, pa[tn][kc], o[vm][tn]);
            }
        }

        __syncthreads();  // drains vmcnt (stage) + lgkm, then barrier
    }

    float inv[2];
    #pragma unroll
    for (int tn = 0; tn < 2; ++tn) inv[tn] = 1.0f / dacc[tn][0];

    // epilogue: attnb[(b*2048+t)*1024 + h*64 + v] = O^T[v][t] * inv
    #pragma unroll
    for (int vm = 0; vm < 4; ++vm)
        #pragma unroll
        for (int tn = 0; tn < 2; ++tn) {
            const int t = twave + tn * 16 + c;
            f32x4 v4;
            #pragma unroll
            for (int r = 0; r < 4; ++r) v4[r] = o[vm][tn][r] * inv[tn];
            bf16x4 pv = __builtin_convertvector(v4, bf16x4);
            *(bf16x4*)(attnb + (size_t)(b * 2048 + t) * 1024 + h * 64 + vm * 16 + g * 4) = pv;
        }
}

// ---------------------------------------------------------------------------
extern "C" void kernel_launch(void* const* d_in, const int* in_sizes, int n_in,
                              void* d_out, int out_size, void* d_ws, size_t ws_size,
                              hipStream_t stream) {
    const float* query = (const float*)d_in[0];
    const float* value = (const float*)d_in[1];
    const int*   mask  = (const int*)d_in[2];
    const float* Wq = (const float*)d_in[3];
    const float* bq = (const float*)d_in[4];
    const float* Wk = (const float*)d_in[5];
    const float* bk = (const float*)d_in[6];
    const float* Wv = (const float*)d_in[7];
    const float* bv = (const float*)d_in[8];
    const float* Wo = (const float*)d_in[9];
    const float* bo = (const float*)d_in[10];

    char* ws = (char*)d_ws;
    unsigned short* WqT   = (unsigned short*)(ws + ((size_t)0  << 20));  // 2 MB (x C_EXP)
    unsigned short* WkT   = (unsigned short*)(ws + ((size_t)2  << 20));  // 2 MB
    unsigned short* WvT   = (unsigned short*)(ws + ((size_t)4  << 20));  // 2 MB
    unsigned short* WoT   = (unsigned short*)(ws + ((size_t)6  << 20));  // 2 MB
    unsigned char*  flags = (unsigned char*) (ws + ((size_t)8  << 20));  // 2 KB
    unsigned short* CONV  = (unsigned short*)(ws + ((size_t)9  << 20));  // 16 MB (Vbf16 -> Qbf16 -> attnb)
    unsigned short* Qp    = (unsigned short*)(ws + ((size_t)25 << 20));  // 16 MB (pre-scaled Q)
    unsigned short* Kp    = (unsigned short*)(ws + ((size_t)41 << 20));  // 16 MB
    unsigned short* VTp   = (unsigned short*)(ws + ((size_t)57 << 20));  // 16 MB ([bh][v][s])

    const int n8 = 8192 * 1024 / 8;
    dim3 gp(8, 64);

    // value -> bf16; K and V projections consume it
    cvt_kernel<<<2048, 256, 0, stream>>>(value, CONV, n8);
    wtrans_kernel<<<dim3(16, 16, 4), 256, 0, stream>>>(Wq, Wk, Wv, Wo, WqT, WkT, WvT, WoT);
    maskflag_kernel<<<2048, 256, 0, stream>>>(mask, flags);
    mm_kernel<0><<<gp, 256, 0, stream>>>(CONV, WkT, bk, 1.0f, Kp);
    mm_kernel<1><<<gp, 256, 0, stream>>>(CONV, WvT, bv, 1.0f, VTp);

    // query -> bf16 (reuses CONV; value-bf16 dead now)
    cvt_kernel<<<2048, 256, 0, stream>>>(query, CONV, n8);
    mm_kernel<0><<<gp, 256, 0, stream>>>(CONV, WqT, bq, C_EXP, Qp);

    // attention writes attnb into CONV (query-bf16 dead now)
    dim3 ga(16, 64);
    attn_kernel<<<ga, 256, 0, stream>>>(Qp, Kp, VTp, mask, flags, CONV);

    mm_kernel<2><<<gp, 256, 0, stream>>>(CONV, WoT, bo, 1.0f, d_out);
}

// Round 7
// 232.785 us; speedup vs baseline: 1.9006x; 1.1670x over previous
//
#include <hip/hip_runtime.h>

typedef __bf16 bf16x8 __attribute__((ext_vector_type(8)));
typedef __bf16 bf16x4 __attribute__((ext_vector_type(4)));
typedef float  f32x4  __attribute__((ext_vector_type(4)));
typedef int    i32x4  __attribute__((ext_vector_type(4)));

typedef __attribute__((address_space(1))) unsigned int as1_u32;
typedef __attribute__((address_space(3))) unsigned int as3_u32;

#define DEVI __device__ __forceinline__

DEVI unsigned short f2bf(float f) {
    union { float f; unsigned u; } v; v.f = f;
    unsigned r = (v.u + 0x7fffu + ((v.u >> 16) & 1u)) >> 16;
    return (unsigned short)r;
}

// direct global->LDS 16B: lane L's 16B lands at ldsbase + L*16
DEVI void gload16(const void* g, void* l) {
    __builtin_amdgcn_global_load_lds((const as1_u32*)g, (as3_u32*)l, 16, 0, 0);
}

// softmax(x/8) = exp2(x * 0.125 * log2(e)); scale folded into Q projection.
#define C_EXP 0.18033688011112042f
// -10000 * log2(e)
#define MASK_ADD (-14426.950408889634f)

// ---------------------------------------------------------------------------
// f32 -> bf16 bulk convert (n8 = elements/8)
// ---------------------------------------------------------------------------
__global__ __launch_bounds__(256) void cvt_kernel(const float* __restrict__ in,
                                                  unsigned short* __restrict__ out,
                                                  int n8) {
    const int stride = gridDim.x * 256;
    for (int idx = blockIdx.x * 256 + threadIdx.x; idx < n8; idx += stride) {
        const f32x4 a = *(const f32x4*)(in + (size_t)idx * 8);
        const f32x4 b = *(const f32x4*)(in + (size_t)idx * 8 + 4);
        union { bf16x4 v[2]; i32x4 q; } u;
        u.v[0] = __builtin_convertvector(a, bf16x4);
        u.v[1] = __builtin_convertvector(b, bf16x4);
        *(i32x4*)(out + (size_t)idx * 8) = u.q;
    }
}

// ---------------------------------------------------------------------------
// Transpose 4x (1024x1024) f32 -> bf16: WT[n][k] = W[k][n]*scale, z selects.
// ---------------------------------------------------------------------------
__global__ __launch_bounds__(256) void wtrans_kernel(const float* __restrict__ W0,
                                                     const float* __restrict__ W1,
                                                     const float* __restrict__ W2,
                                                     const float* __restrict__ W3,
                                                     unsigned short* __restrict__ T0,
                                                     unsigned short* __restrict__ T1,
                                                     unsigned short* __restrict__ T2,
                                                     unsigned short* __restrict__ T3) {
    __shared__ float tile[64][65];
    const float* W;
    unsigned short* WT;
    float scale = 1.0f;
    switch (blockIdx.z) {
        case 0:  W = W0; WT = T0; scale = C_EXP; break;
        case 1:  W = W1; WT = T1; break;
        case 2:  W = W2; WT = T2; break;
        default: W = W3; WT = T3; break;
    }
    const int k0 = blockIdx.x * 64, n0 = blockIdx.y * 64;
    const int i = threadIdx.x;
    const int c4 = (i & 15) * 4, rbase = i >> 4;
    for (int rr = 0; rr < 4; ++rr) {
        const int kl = rbase + rr * 16;
        const float4 v = *(const float4*)(W + (size_t)(k0 + kl) * 1024 + n0 + c4);
        tile[kl][c4 + 0] = v.x; tile[kl][c4 + 1] = v.y;
        tile[kl][c4 + 2] = v.z; tile[kl][c4 + 3] = v.w;
    }
    __syncthreads();
    for (int rr = 0; rr < 4; ++rr) {
        const int nl = rbase + rr * 16;
        ushort4 o;
        o.x = f2bf(tile[c4 + 0][nl] * scale); o.y = f2bf(tile[c4 + 1][nl] * scale);
        o.z = f2bf(tile[c4 + 2][nl] * scale); o.w = f2bf(tile[c4 + 3][nl] * scale);
        *(ushort4*)(WT + (size_t)(n0 + nl) * 1024 + k0 + c4) = o;
    }
}

// ---------------------------------------------------------------------------
// Mask all-true flags per (b, 128-row t-tile, 64-col s-tile). mask is int32.
// ---------------------------------------------------------------------------
__global__ __launch_bounds__(256) void maskflag_kernel(const int* __restrict__ mask,
                                                       unsigned char* __restrict__ flags) {
    const int bid = blockIdx.x;
    const int b = bid >> 9, rem = bid & 511;
    const int tb = rem >> 5, si = rem & 31;
    const int i = threadIdx.x;
    const int t = tb * 128 + (i >> 1);
    const int s = si * 64 + (i & 1) * 32;
    const uint4* p = (const uint4*)(mask + ((size_t)(b * 2048 + t)) * 2048 + s);
    int ok = 1;
    #pragma unroll
    for (int u = 0; u < 8; ++u) {
        const uint4 a = p[u];
        ok &= (a.x != 0) & (a.y != 0) & (a.z != 0) & (a.w != 0);
    }
    int all = __syncthreads_and(ok);
    if (i == 0) flags[bid] = (unsigned char)all;
}

// ---------------------------------------------------------------------------
// Unified bf16 GEMM, m97-style: C[m,n] = A[m,:] . BT[n,:] + bias[n]*bscale
// 128x128 tile, BK=32, 4 waves, global_load_lds w16, XCD-swizzled 1D grid:
// all 8 n-blocks of an m-panel land on the same XCD (A fetched once).
// MODE 0: bf16 scatter [b][h][t][c];  MODE 1: bf16 V^T [b][h][c][t];
// MODE 2: f32 linear [m][n].
// ---------------------------------------------------------------------------
template <int MODE>
__global__ __launch_bounds__(256) void mm_kernel(const unsigned short* __restrict__ A,
                                                 const unsigned short* __restrict__ BT,
                                                 const float* __restrict__ bias,
                                                 float bscale,
                                                 void* __restrict__ Ov) {
    __shared__ __align__(16) unsigned short Ab[128 * 32];
    __shared__ __align__(16) unsigned short Bb[128 * 32];
    const int bid = blockIdx.x;
    const int xcd = bid & 7, jj = bid >> 3;
    const int n0 = (jj & 7) * 128;
    const int m0 = ((jj >> 3) * 8 + xcd) * 128;
    const int i = threadIdx.x, w = i >> 6, l = i & 63;
    const int wm = w >> 1, wn = w & 1;
    const int c = l & 15, g = l >> 4;
    const int rloc = l >> 2;
    const int schunk = ((l & 3) ^ ((l >> 3) & 3)) * 8;
    const int rs = (c >> 1) & 3;

    f32x4 acc[4][4] = {};

    const unsigned short* Asrc = A + (size_t)(m0 + w * 32 + rloc) * 1024 + schunk;
    const unsigned short* Bsrc = BT + (size_t)(n0 + w * 32 + rloc) * 1024 + schunk;
    unsigned short* AbBase = &Ab[(w * 32) * 32];
    unsigned short* BbBase = &Bb[(w * 32) * 32];

    for (int k0 = 0; k0 < 1024; k0 += 32) {
        gload16(Asrc + k0,             AbBase);
        gload16(Asrc + k0 + 16 * 1024, AbBase + 16 * 32);
        gload16(Bsrc + k0,             BbBase);
        gload16(Bsrc + k0 + 16 * 1024, BbBase + 16 * 32);
        __syncthreads();
        bf16x8 af[4], bfr[4];
        #pragma unroll
        for (int mf = 0; mf < 4; ++mf)
            af[mf] = *(const bf16x8*)&Ab[(wm * 64 + mf * 16 + c) * 32 + (g ^ rs) * 8];
        #pragma unroll
        for (int nf = 0; nf < 4; ++nf)
            bfr[nf] = *(const bf16x8*)&Bb[(wn * 64 + nf * 16 + c) * 32 + (g ^ rs) * 8];
        #pragma unroll
        for (int mf = 0; mf < 4; ++mf)
            #pragma unroll
            for (int nf = 0; nf < 4; ++nf)
                acc[mf][nf] = __builtin_amdgcn_mfma_f32_16x16x32_bf16(af[mf], bfr[nf], acc[mf][nf], 0, 0, 0);
        __syncthreads();
    }

    #pragma unroll
    for (int nf = 0; nf < 4; ++nf) {
        const int n = n0 + wn * 64 + nf * 16 + c;
        const float bv = bias[n] * bscale;
        const int h = n >> 6, cc = n & 63;
        #pragma unroll
        for (int mf = 0; mf < 4; ++mf) {
            const int mbase = m0 + wm * 64 + mf * 16 + g * 4;
            if (MODE == 0) {
                const int b = mbase >> 11, t = mbase & 2047;
                unsigned short* O = (unsigned short*)Ov;
                #pragma unroll
                for (int r = 0; r < 4; ++r)
                    O[(((size_t)(b * 16 + h)) * 2048 + t + r) * 64 + cc] = f2bf(acc[mf][nf][r] + bv);
            } else if (MODE == 1) {
                const int b = mbase >> 11, t = mbase & 2047;
                f32x4 v;
                #pragma unroll
                for (int r = 0; r < 4; ++r) v[r] = acc[mf][nf][r] + bv;
                bf16x4 pv = __builtin_convertvector(v, bf16x4);
                unsigned short* O = (unsigned short*)Ov;
                *(bf16x4*)(O + (((size_t)(b * 16 + h)) * 64 + cc) * 2048 + t) = pv;
            } else {
                float* O = (float*)Ov;
                #pragma unroll
                for (int r = 0; r < 4; ++r)
                    O[(size_t)(mbase + r) * 1024 + n] = acc[mf][nf][r] + bv;
            }
        }
    }
}

// ---------------------------------------------------------------------------
// Flash attention, swapped QK^T with PERMUTED K rows so the S^T output
// C-layout concatenates directly into the K32 PV B-fragment (P stays in
// registers, no LDS, no cross-lane). Row feed: A row u of kf(sm) holds
// K[orig(sm,u)], orig(sm,u) = (sm>>1)*32 + (u>>2)*8 + (sm&1)*4 + (u&3).
// Then lane g's pk-dwords {pk0[2k],pk1[2k],pk0[2k+1],pk1[2k+1]} = B-frag
// k = g*8+j for PV chunk k. Staging swizzle swz(r) = (r ^ (r>>2)) & 7
// spreads both the permuted kf reads and Vt reads conflict-free.
// XCD swizzle: each XCD owns 8 bh x 16 tb (K/V 4MB = L2-resident).
// grid = 1024 (1D), 4 waves. Denominator via ones-MFMA (K32).
// ---------------------------------------------------------------------------
__global__ __launch_bounds__(256) void attn_kernel(const unsigned short* __restrict__ Qp,
                                                   const unsigned short* __restrict__ Kp,
                                                   const unsigned short* __restrict__ VTp,
                                                   const int* __restrict__ mask,
                                                   const unsigned char* __restrict__ flags,
                                                   unsigned short* __restrict__ attnb) {
    __shared__ __align__(16) unsigned short Kt[2][64 * 64];  // [s][dk], swizzled chunks
    __shared__ __align__(16) unsigned short Vt[2][64 * 64];  // [v][s],  swizzled chunks

    const int bid = blockIdx.x;
    const int xcd = bid & 7, jj = bid >> 3;
    const int bh = xcd * 8 + (jj >> 4);
    const int tb = jj & 15;
    const int b = bh >> 4, h = bh & 15;
    const int i = threadIdx.x, w = i >> 6, l = i & 63;
    const int c = l & 15, g = l >> 4;

    const unsigned short* Qb  = Qp  + (size_t)bh * 2048 * 64;
    const unsigned short* Kb  = Kp  + (size_t)bh * 2048 * 64;
    const unsigned short* VTb = VTp + (size_t)bh * 64 * 2048;

    const int twave = tb * 128 + w * 32;

    // Q as B-operand (K32): lane holds Q[t = twave+tn*16+c][dk = kq*32+g*8+j]
    bf16x8 qf[2][2];
    #pragma unroll
    for (int tn = 0; tn < 2; ++tn)
        #pragma unroll
        for (int kq = 0; kq < 2; ++kq)
            qf[tn][kq] = *(const bf16x8*)(Qb + (size_t)(twave + tn * 16 + c) * 64 + kq * 32 + g * 8);

    f32x4 o[4][2] = {};     // O^T accum: v = vm*16+g*4+r, t = twave+tn*16+c
    f32x4 dacc[2] = {};     // denominator via ones-MFMA

    bf16x8 ones8;
    #pragma unroll
    for (int j = 0; j < 8; ++j) ones8[j] = (__bf16)1.0f;

    // kf read rows (permuted) + their chunk swizzles, per sm
    int rrow[4], rswz[4];
    #pragma unroll
    for (int sm = 0; sm < 4; ++sm) {
        rrow[sm] = (sm >> 1) * 32 + (c >> 2) * 8 + (sm & 1) * 4 + (c & 3);
        rswz[sm] = (rrow[sm] ^ (rrow[sm] >> 2)) & 7;
    }
    // Vt read rows + swizzles, per vm
    int vswz[4];
    #pragma unroll
    for (int vm = 0; vm < 4; ++vm) {
        const int rv = vm * 16 + c;
        vswz[vm] = (rv ^ (rv >> 2)) & 7;
    }

    // staging: lane L -> LDS (row = base + L>>3, slot L&7); source chunk
    // = (L&7) ^ swz(row) so LDS slot s of row r holds global chunk s ^ swz(r).
    const int srow = l >> 3, sslot = l & 7;

    #pragma unroll
    for (int u = 0; u < 2; ++u) {
        const int row = w * 16 + u * 8 + srow;
        const int ch = sslot ^ ((row ^ (row >> 2)) & 7);
        gload16(Kb + (size_t)row * 64 + ch * 8, &Kt[0][(w * 16 + u * 8) * 64]);
        gload16(VTb + (size_t)row * 2048 + ch * 8, &Vt[0][(w * 16 + u * 8) * 64]);
    }
    __syncthreads();

    for (int it = 0; it < 32; ++it) {
        const int buf = it & 1;
        const int s0 = it * 64;

        // issue next-tile stage (lands in buf^1; drained by end-of-iter barrier)
        if (it < 31) {
            const int s0n = s0 + 64;
            #pragma unroll
            for (int u = 0; u < 2; ++u) {
                const int row = w * 16 + u * 8 + srow;
                const int ch = sslot ^ ((row ^ (row >> 2)) & 7);
                gload16(Kb + (size_t)(s0n + row) * 64 + ch * 8, &Kt[buf ^ 1][(w * 16 + u * 8) * 64]);
                gload16(VTb + (size_t)row * 2048 + s0n + ch * 8, &Vt[buf ^ 1][(w * 16 + u * 8) * 64]);
            }
        }

        // QK^T swapped, permuted rows: sc[sm][tn][r] = S^T at
        // s = s0 + (sm>>1)*32 + g*8 + (sm&1)*4 + r,  t = twave + tn*16 + c
        f32x4 sc[4][2] = {};
        #pragma unroll
        for (int sm = 0; sm < 4; ++sm)
            #pragma unroll
            for (int kq = 0; kq < 2; ++kq) {
                const bf16x8 kf = *(const bf16x8*)&Kt[buf][rrow[sm] * 64 + (((kq * 4 + g) ^ rswz[sm]) * 8)];
                #pragma unroll
                for (int tn = 0; tn < 2; ++tn)
                    sc[sm][tn] = __builtin_amdgcn_mfma_f32_16x16x32_bf16(kf, qf[tn][kq], sc[sm][tn], 0, 0, 0);
            }

        // mask fallback (exp2 domain), permuted s indexing
        const int flg = flags[(b * 16 + tb) * 32 + it];
        if (!flg) {
            #pragma unroll
            for (int sm = 0; sm < 4; ++sm)
                #pragma unroll
                for (int tn = 0; tn < 2; ++tn)
                    #pragma unroll
                    for (int r = 0; r < 4; ++r) {
                        const int t = twave + tn * 16 + c;
                        const int s = s0 + (sm >> 1) * 32 + g * 8 + (sm & 1) * 4 + r;
                        if (mask[(size_t)(b * 2048 + t) * 2048 + s] == 0) sc[sm][tn][r] += MASK_ADD;
                    }
        }

        // p = exp2(sc); pack to bf16 dwords (rows g*4+{0,1} and g*4+{2,3})
        unsigned pk[4][2][2];
        #pragma unroll
        for (int sm = 0; sm < 4; ++sm)
            #pragma unroll
            for (int tn = 0; tn < 2; ++tn) {
                f32x4 p;
                #pragma unroll
                for (int r = 0; r < 4; ++r)
                    p[r] = __builtin_amdgcn_exp2f(sc[sm][tn][r]);
                union { bf16x4 v; unsigned d[2]; } u;
                u.v = __builtin_convertvector(p, bf16x4);
                pk[sm][tn][0] = u.d[0];
                pk[sm][tn][1] = u.d[1];
            }

        // PV (K32): pa[tn] for chunk kv is the direct dword concat
        #pragma unroll
        for (int kv = 0; kv < 2; ++kv) {
            bf16x8 pa[2];
            #pragma unroll
            for (int tn = 0; tn < 2; ++tn) {
                union { i32x4 q; bf16x8 v; } pu;
                pu.q[0] = (int)pk[kv * 2][tn][0];
                pu.q[1] = (int)pk[kv * 2][tn][1];
                pu.q[2] = (int)pk[kv * 2 + 1][tn][0];
                pu.q[3] = (int)pk[kv * 2 + 1][tn][1];
                pa[tn] = pu.v;
            }
            #pragma unroll
            for (int tn = 0; tn < 2; ++tn)
                dacc[tn] = __builtin_amdgcn_mfma_f32_16x16x32_bf16(ones8, pa[tn], dacc[tn], 0, 0, 0);
            #pragma unroll
            for (int vm = 0; vm < 4; ++vm) {
                const bf16x8 vf = *(const bf16x8*)&Vt[buf][(vm * 16 + c) * 64 + (((kv * 4 + g) ^ vswz[vm]) * 8)];
                #pragma unroll
                for (int tn = 0; tn < 2; ++tn)
                    o[vm][tn] = __builtin_amdgcn_mfma_f32_16x16x32_bf16(vf, pa[tn], o[vm][tn], 0, 0, 0);
            }
        }

        __syncthreads();  // drains vmcnt (stage) + lgkm, then barrier
    }

    float inv[2];
    #pragma unroll
    for (int tn = 0; tn < 2; ++tn) inv[tn] = 1.0f / dacc[tn][0];

    // epilogue: attnb[(b*2048+t)*1024 + h*64 + v] = O^T[v][t] * inv
    #pragma unroll
    for (int vm = 0; vm < 4; ++vm)
        #pragma unroll
        for (int tn = 0; tn < 2; ++tn) {
            const int t = twave + tn * 16 + c;
            f32x4 v4;
            #pragma unroll
            for (int r = 0; r < 4; ++r) v4[r] = o[vm][tn][r] * inv[tn];
            bf16x4 pv = __builtin_convertvector(v4, bf16x4);
            *(bf16x4*)(attnb + (size_t)(b * 2048 + t) * 1024 + h * 64 + vm * 16 + g * 4) = pv;
        }
}

// ---------------------------------------------------------------------------
extern "C" void kernel_launch(void* const* d_in, const int* in_sizes, int n_in,
                              void* d_out, int out_size, void* d_ws, size_t ws_size,
                              hipStream_t stream) {
    const float* query = (const float*)d_in[0];
    const float* value = (const float*)d_in[1];
    const int*   mask  = (const int*)d_in[2];
    const float* Wq = (const float*)d_in[3];
    const float* bq = (const float*)d_in[4];
    const float* Wk = (const float*)d_in[5];
    const float* bk = (const float*)d_in[6];
    const float* Wv = (const float*)d_in[7];
    const float* bv = (const float*)d_in[8];
    const float* Wo = (const float*)d_in[9];
    const float* bo = (const float*)d_in[10];

    char* ws = (char*)d_ws;
    unsigned short* WqT   = (unsigned short*)(ws + ((size_t)0  << 20));  // 2 MB (x C_EXP)
    unsigned short* WkT   = (unsigned short*)(ws + ((size_t)2  << 20));  // 2 MB
    unsigned short* WvT   = (unsigned short*)(ws + ((size_t)4  << 20));  // 2 MB
    unsigned short* WoT   = (unsigned short*)(ws + ((size_t)6  << 20));  // 2 MB
    unsigned char*  flags = (unsigned char*) (ws + ((size_t)8  << 20));  // 2 KB
    unsigned short* CONV  = (unsigned short*)(ws + ((size_t)9  << 20));  // 16 MB (Vbf16 -> Qbf16 -> attnb)
    unsigned short* Qp    = (unsigned short*)(ws + ((size_t)25 << 20));  // 16 MB (pre-scaled Q)
    unsigned short* Kp    = (unsigned short*)(ws + ((size_t)41 << 20));  // 16 MB
    unsigned short* VTp   = (unsigned short*)(ws + ((size_t)57 << 20));  // 16 MB ([bh][v][s])

    const int n8 = 8192 * 1024 / 8;

    // value -> bf16; K and V projections consume it
    cvt_kernel<<<2048, 256, 0, stream>>>(value, CONV, n8);
    wtrans_kernel<<<dim3(16, 16, 4), 256, 0, stream>>>(Wq, Wk, Wv, Wo, WqT, WkT, WvT, WoT);
    maskflag_kernel<<<2048, 256, 0, stream>>>(mask, flags);
    mm_kernel<0><<<512, 256, 0, stream>>>(CONV, WkT, bk, 1.0f, Kp);
    mm_kernel<1><<<512, 256, 0, stream>>>(CONV, WvT, bv, 1.0f, VTp);

    // query -> bf16 (reuses CONV; value-bf16 dead now)
    cvt_kernel<<<2048, 256, 0, stream>>>(query, CONV, n8);
    mm_kernel<0><<<512, 256, 0, stream>>>(CONV, WqT, bq, C_EXP, Qp);

    // attention writes attnb into CONV (query-bf16 dead now)
    attn_kernel<<<1024, 256, 0, stream>>>(Qp, Kp, VTp, mask, flags, CONV);

    mm_kernel<2><<<512, 256, 0, stream>>>(CONV, WoT, bo, 1.0f, (float*)d_out);
}

// Round 8
// 224.237 us; speedup vs baseline: 1.9731x; 1.0381x over previous
//
#include <hip/hip_runtime.h>

typedef __bf16 bf16x8 __attribute__((ext_vector_type(8)));
typedef __bf16 bf16x4 __attribute__((ext_vector_type(4)));
typedef float  f32x4  __attribute__((ext_vector_type(4)));
typedef int    i32x4  __attribute__((ext_vector_type(4)));

typedef __attribute__((address_space(1))) unsigned int as1_u32;
typedef __attribute__((address_space(3))) unsigned int as3_u32;

#define DEVI __device__ __forceinline__

DEVI unsigned short f2bf(float f) {
    union { float f; unsigned u; } v; v.f = f;
    unsigned r = (v.u + 0x7fffu + ((v.u >> 16) & 1u)) >> 16;
    return (unsigned short)r;
}

// direct global->LDS 16B: lane L's 16B lands at ldsbase + L*16
DEVI void gload16(const void* g, void* l) {
    __builtin_amdgcn_global_load_lds((const as1_u32*)g, (as3_u32*)l, 16, 0, 0);
}

// softmax(x/8) = exp2(x * 0.125 * log2(e)); scale folded into Q projection.
#define C_EXP 0.18033688011112042f
// -10000 * log2(e)
#define MASK_ADD (-14426.950408889634f)

// ---------------------------------------------------------------------------
// f32 -> bf16 bulk convert (n8 = elements/8)
// ---------------------------------------------------------------------------
__global__ __launch_bounds__(256) void cvt_kernel(const float* __restrict__ in,
                                                  unsigned short* __restrict__ out,
                                                  int n8) {
    const int stride = gridDim.x * 256;
    for (int idx = blockIdx.x * 256 + threadIdx.x; idx < n8; idx += stride) {
        const f32x4 a = *(const f32x4*)(in + (size_t)idx * 8);
        const f32x4 b = *(const f32x4*)(in + (size_t)idx * 8 + 4);
        union { bf16x4 v[2]; i32x4 q; } u;
        u.v[0] = __builtin_convertvector(a, bf16x4);
        u.v[1] = __builtin_convertvector(b, bf16x4);
        *(i32x4*)(out + (size_t)idx * 8) = u.q;
    }
}

// ---------------------------------------------------------------------------
// Transpose 4x (1024x1024) f32 -> bf16: WT[n][k] = W[k][n]*scale, z selects.
// ---------------------------------------------------------------------------
__global__ __launch_bounds__(256) void wtrans_kernel(const float* __restrict__ W0,
                                                     const float* __restrict__ W1,
                                                     const float* __restrict__ W2,
                                                     const float* __restrict__ W3,
                                                     unsigned short* __restrict__ T0,
                                                     unsigned short* __restrict__ T1,
                                                     unsigned short* __restrict__ T2,
                                                     unsigned short* __restrict__ T3) {
    __shared__ float tile[64][65];
    const float* W;
    unsigned short* WT;
    float scale = 1.0f;
    switch (blockIdx.z) {
        case 0:  W = W0; WT = T0; scale = C_EXP; break;
        case 1:  W = W1; WT = T1; break;
        case 2:  W = W2; WT = T2; break;
        default: W = W3; WT = T3; break;
    }
    const int k0 = blockIdx.x * 64, n0 = blockIdx.y * 64;
    const int i = threadIdx.x;
    const int c4 = (i & 15) * 4, rbase = i >> 4;
    for (int rr = 0; rr < 4; ++rr) {
        const int kl = rbase + rr * 16;
        const float4 v = *(const float4*)(W + (size_t)(k0 + kl) * 1024 + n0 + c4);
        tile[kl][c4 + 0] = v.x; tile[kl][c4 + 1] = v.y;
        tile[kl][c4 + 2] = v.z; tile[kl][c4 + 3] = v.w;
    }
    __syncthreads();
    for (int rr = 0; rr < 4; ++rr) {
        const int nl = rbase + rr * 16;
        ushort4 o;
        o.x = f2bf(tile[c4 + 0][nl] * scale); o.y = f2bf(tile[c4 + 1][nl] * scale);
        o.z = f2bf(tile[c4 + 2][nl] * scale); o.w = f2bf(tile[c4 + 3][nl] * scale);
        *(ushort4*)(WT + (size_t)(n0 + nl) * 1024 + k0 + c4) = o;
    }
}

// ---------------------------------------------------------------------------
// Mask not-all-true bits: word[(b*16+tb128)] bit si set if any zero in the
// (b, 128-row t-tile, 64-col s-tile). mask is int32. flagsW pre-zeroed.
// ---------------------------------------------------------------------------
__global__ __launch_bounds__(256) void maskflag_kernel(const int* __restrict__ mask,
                                                       unsigned* __restrict__ flagsW) {
    const int bid = blockIdx.x;
    const int b = bid >> 9, rem = bid & 511;
    const int tb = rem >> 5, si = rem & 31;
    const int i = threadIdx.x;
    const int t = tb * 128 + (i >> 1);
    const int s = si * 64 + (i & 1) * 32;
    const uint4* p = (const uint4*)(mask + ((size_t)(b * 2048 + t)) * 2048 + s);
    int ok = 1;
    #pragma unroll
    for (int u = 0; u < 8; ++u) {
        const uint4 a = p[u];
        ok &= (a.x != 0) & (a.y != 0) & (a.z != 0) & (a.w != 0);
    }
    int all = __syncthreads_and(ok);
    if (i == 0 && !all) atomicOr(&flagsW[b * 16 + tb], 1u << si);
}

// ---------------------------------------------------------------------------
// Unified bf16 GEMM, m97-style: C[m,n] = A[m,:] . BT[n,:] + bias[n]*bscale
// 128x128 tile, BK=32, 4 waves, global_load_lds w16, XCD-swizzled 1D grid.
// MODE 0: bf16 scatter [b][h][t][c];  MODE 1: bf16 V^T [b][h][c][t];
// MODE 2: f32 linear [m][n].
// ---------------------------------------------------------------------------
template <int MODE>
__global__ __launch_bounds__(256) void mm_kernel(const unsigned short* __restrict__ A,
                                                 const unsigned short* __restrict__ BT,
                                                 const float* __restrict__ bias,
                                                 float bscale,
                                                 void* __restrict__ Ov) {
    __shared__ __align__(16) unsigned short Ab[128 * 32];
    __shared__ __align__(16) unsigned short Bb[128 * 32];
    const int bid = blockIdx.x;
    const int xcd = bid & 7, jj = bid >> 3;
    const int n0 = (jj & 7) * 128;
    const int m0 = ((jj >> 3) * 8 + xcd) * 128;
    const int i = threadIdx.x, w = i >> 6, l = i & 63;
    const int wm = w >> 1, wn = w & 1;
    const int c = l & 15, g = l >> 4;
    const int rloc = l >> 2;
    const int schunk = ((l & 3) ^ ((l >> 3) & 3)) * 8;
    const int rs = (c >> 1) & 3;

    f32x4 acc[4][4] = {};

    const unsigned short* Asrc = A + (size_t)(m0 + w * 32 + rloc) * 1024 + schunk;
    const unsigned short* Bsrc = BT + (size_t)(n0 + w * 32 + rloc) * 1024 + schunk;
    unsigned short* AbBase = &Ab[(w * 32) * 32];
    unsigned short* BbBase = &Bb[(w * 32) * 32];

    for (int k0 = 0; k0 < 1024; k0 += 32) {
        gload16(Asrc + k0,             AbBase);
        gload16(Asrc + k0 + 16 * 1024, AbBase + 16 * 32);
        gload16(Bsrc + k0,             BbBase);
        gload16(Bsrc + k0 + 16 * 1024, BbBase + 16 * 32);
        __syncthreads();
        bf16x8 af[4], bfr[4];
        #pragma unroll
        for (int mf = 0; mf < 4; ++mf)
            af[mf] = *(const bf16x8*)&Ab[(wm * 64 + mf * 16 + c) * 32 + (g ^ rs) * 8];
        #pragma unroll
        for (int nf = 0; nf < 4; ++nf)
            bfr[nf] = *(const bf16x8*)&Bb[(wn * 64 + nf * 16 + c) * 32 + (g ^ rs) * 8];
        #pragma unroll
        for (int mf = 0; mf < 4; ++mf)
            #pragma unroll
            for (int nf = 0; nf < 4; ++nf)
                acc[mf][nf] = __builtin_amdgcn_mfma_f32_16x16x32_bf16(af[mf], bfr[nf], acc[mf][nf], 0, 0, 0);
        __syncthreads();
    }

    #pragma unroll
    for (int nf = 0; nf < 4; ++nf) {
        const int n = n0 + wn * 64 + nf * 16 + c;
        const float bv = bias[n] * bscale;
        const int h = n >> 6, cc = n & 63;
        #pragma unroll
        for (int mf = 0; mf < 4; ++mf) {
            const int mbase = m0 + wm * 64 + mf * 16 + g * 4;
            if (MODE == 0) {
                const int b = mbase >> 11, t = mbase & 2047;
                unsigned short* O = (unsigned short*)Ov;
                #pragma unroll
                for (int r = 0; r < 4; ++r)
                    O[(((size_t)(b * 16 + h)) * 2048 + t + r) * 64 + cc] = f2bf(acc[mf][nf][r] + bv);
            } else if (MODE == 1) {
                const int b = mbase >> 11, t = mbase & 2047;
                f32x4 v;
                #pragma unroll
                for (int r = 0; r < 4; ++r) v[r] = acc[mf][nf][r] + bv;
                bf16x4 pv = __builtin_convertvector(v, bf16x4);
                unsigned short* O = (unsigned short*)Ov;
                *(bf16x4*)(O + (((size_t)(b * 16 + h)) * 64 + cc) * 2048 + t) = pv;
            } else {
                float* O = (float*)Ov;
                #pragma unroll
                for (int r = 0; r < 4; ++r)
                    O[(size_t)(mbase + r) * 1024 + n] = acc[mf][nf][r] + bv;
            }
        }
    }
}

// ---------------------------------------------------------------------------
// Flash attention, swapped QK^T with PERMUTED K rows (P in registers, K32 PV).
// 16 Q-rows per wave (QBLK=64), 4 waves, grid 2048. __launch_bounds__(256,5)
// caps VGPR at 102 -> 5 blocks/CU (LDS 5x32KB = 160KB). Flags read once into
// an SGPR bitword (scalar per-iter test). setprio around MFMA clusters.
// XCD swizzle: each XCD owns 8 bh x 32 tb (K/V 4MB = L2-resident).
// ---------------------------------------------------------------------------
__global__ __launch_bounds__(256, 5) void attn_kernel(const unsigned short* __restrict__ Qp,
                                                      const unsigned short* __restrict__ Kp,
                                                      const unsigned short* __restrict__ VTp,
                                                      const int* __restrict__ mask,
                                                      const unsigned* __restrict__ flagsW,
                                                      unsigned short* __restrict__ attnb) {
    __shared__ __align__(16) unsigned short Kt[2][64 * 64];  // [s][dk], swizzled chunks
    __shared__ __align__(16) unsigned short Vt[2][64 * 64];  // [v][s],  swizzled chunks

    const int bid = blockIdx.x;
    const int xcd = bid & 7, jj = bid >> 3;       // jj in 0..255
    const int bh = xcd * 8 + (jj >> 5);           // 8 bh per XCD
    const int tb = jj & 31;                       // 32 x 64-row t-tiles
    const int b = bh >> 4, h = bh & 15;
    const int i = threadIdx.x, w = i >> 6, l = i & 63;
    const int c = l & 15, g = l >> 4;

    const unsigned short* Qb  = Qp  + (size_t)bh * 2048 * 64;
    const unsigned short* Kb  = Kp  + (size_t)bh * 2048 * 64;
    const unsigned short* VTb = VTp + (size_t)bh * 64 * 2048;

    const int twave = tb * 64 + w * 16;

    // not-all-true bits for this 128-row region (wave-uniform, to SGPR)
    const unsigned notall = __builtin_amdgcn_readfirstlane(flagsW[b * 16 + (tb >> 1)]);

    // Q as B-operand (K32): lane holds Q[t = twave+c][dk = kq*32+g*8+j]
    bf16x8 qf[2];
    #pragma unroll
    for (int kq = 0; kq < 2; ++kq)
        qf[kq] = *(const bf16x8*)(Qb + (size_t)(twave + c) * 64 + kq * 32 + g * 8);

    f32x4 o[4] = {};     // O^T accum: v = vm*16+g*4+r, t = twave+c
    f32x4 dacc = {};     // denominator via ones-MFMA

    bf16x8 ones8;
    #pragma unroll
    for (int j = 0; j < 8; ++j) ones8[j] = (__bf16)1.0f;

    // kf read rows (permuted) + chunk swizzles, per sm
    int rrow[4], rswz[4];
    #pragma unroll
    for (int sm = 0; sm < 4; ++sm) {
        rrow[sm] = (sm >> 1) * 32 + (c >> 2) * 8 + (sm & 1) * 4 + (c & 3);
        rswz[sm] = (rrow[sm] ^ (rrow[sm] >> 2)) & 7;
    }
    int vswz[4];
    #pragma unroll
    for (int vm = 0; vm < 4; ++vm) {
        const int rv = vm * 16 + c;
        vswz[vm] = (rv ^ (rv >> 2)) & 7;
    }

    // staging: lane L -> LDS (row = base + L>>3, slot L&7); source chunk
    // = (L&7) ^ swz(row) so LDS slot s of row r holds global chunk s ^ swz(r).
    const int srow = l >> 3, sslot = l & 7;

    // prologue: stage tile 0 into buffer 0; set up running stage pointers (tile 1)
    const unsigned short* kstage[2];
    const unsigned short* vstage[2];
    #pragma unroll
    for (int u = 0; u < 2; ++u) {
        const int row = w * 16 + u * 8 + srow;
        const int ch = sslot ^ ((row ^ (row >> 2)) & 7);
        gload16(Kb + (size_t)row * 64 + ch * 8, &Kt[0][(w * 16 + u * 8) * 64]);
        gload16(VTb + (size_t)row * 2048 + ch * 8, &Vt[0][(w * 16 + u * 8) * 64]);
        kstage[u] = Kb + (size_t)(64 + row) * 64 + ch * 8;
        vstage[u] = VTb + (size_t)row * 2048 + 64 + ch * 8;
    }
    __syncthreads();

    #pragma unroll 2
    for (int it = 0; it < 32; ++it) {
        const int buf = it & 1;
        const int s0 = it * 64;

        // issue next-tile stage (lands in buf^1; drained by end-of-iter barrier)
        if (it < 31) {
            #pragma unroll
            for (int u = 0; u < 2; ++u) {
                gload16(kstage[u], &Kt[buf ^ 1][(w * 16 + u * 8) * 64]);
                gload16(vstage[u], &Vt[buf ^ 1][(w * 16 + u * 8) * 64]);
                kstage[u] += 64 * 64;
                vstage[u] += 64;
            }
        }

        // QK^T swapped, permuted rows: sc[sm][r] = S^T at
        // s = s0 + (sm>>1)*32 + g*8 + (sm&1)*4 + r,  t = twave + c
        f32x4 sc[4] = {};
        __builtin_amdgcn_s_setprio(1);
        #pragma unroll
        for (int sm = 0; sm < 4; ++sm)
            #pragma unroll
            for (int kq = 0; kq < 2; ++kq) {
                const bf16x8 kf = *(const bf16x8*)&Kt[buf][rrow[sm] * 64 + (((kq * 4 + g) ^ rswz[sm]) * 8)];
                sc[sm] = __builtin_amdgcn_mfma_f32_16x16x32_bf16(kf, qf[kq], sc[sm], 0, 0, 0);
            }
        __builtin_amdgcn_s_setprio(0);

        // mask fallback (exp2 domain), permuted s indexing (scalar-skipped)
        if (notall & (1u << it)) {
            #pragma unroll
            for (int sm = 0; sm < 4; ++sm)
                #pragma unroll
                for (int r = 0; r < 4; ++r) {
                    const int t = twave + c;
                    const int s = s0 + (sm >> 1) * 32 + g * 8 + (sm & 1) * 4 + r;
                    if (mask[(size_t)(b * 2048 + t) * 2048 + s] == 0) sc[sm][r] += MASK_ADD;
                }
        }

        // p = exp2(sc); pack directly into K32 PV B-fragments
        bf16x8 pa[2];
        #pragma unroll
        for (int kv = 0; kv < 2; ++kv) {
            f32x4 p0, p1;
            #pragma unroll
            for (int r = 0; r < 4; ++r) {
                p0[r] = __builtin_amdgcn_exp2f(sc[kv * 2][r]);
                p1[r] = __builtin_amdgcn_exp2f(sc[kv * 2 + 1][r]);
            }
            union { struct { bf16x4 lo, hi; } h; bf16x8 v; } u;
            u.h.lo = __builtin_convertvector(p0, bf16x4);
            u.h.hi = __builtin_convertvector(p1, bf16x4);
            pa[kv] = u.v;
        }

        // PV (K32) + denominator
        __builtin_amdgcn_s_setprio(1);
        #pragma unroll
        for (int kv = 0; kv < 2; ++kv) {
            dacc = __builtin_amdgcn_mfma_f32_16x16x32_bf16(ones8, pa[kv], dacc, 0, 0, 0);
            #pragma unroll
            for (int vm = 0; vm < 4; ++vm) {
                const bf16x8 vf = *(const bf16x8*)&Vt[buf][(vm * 16 + c) * 64 + (((kv * 4 + g) ^ vswz[vm]) * 8)];
                o[vm] = __builtin_amdgcn_mfma_f32_16x16x32_bf16(vf, pa[kv], o[vm], 0, 0, 0);
            }
        }
        __builtin_amdgcn_s_setprio(0);

        __syncthreads();  // drains vmcnt (stage) + lgkm, then barrier
    }

    const float inv = 1.0f / dacc[0];

    // epilogue: attnb[(b*2048+t)*1024 + h*64 + v] = O^T[v][t] * inv
    const int t = twave + c;
    #pragma unroll
    for (int vm = 0; vm < 4; ++vm) {
        f32x4 v4;
        #pragma unroll
        for (int r = 0; r < 4; ++r) v4[r] = o[vm][r] * inv;
        bf16x4 pv = __builtin_convertvector(v4, bf16x4);
        *(bf16x4*)(attnb + (size_t)(b * 2048 + t) * 1024 + h * 64 + vm * 16 + g * 4) = pv;
    }
}

// ---------------------------------------------------------------------------
extern "C" void kernel_launch(void* const* d_in, const int* in_sizes, int n_in,
                              void* d_out, int out_size, void* d_ws, size_t ws_size,
                              hipStream_t stream) {
    const float* query = (const float*)d_in[0];
    const float* value = (const float*)d_in[1];
    const int*   mask  = (const int*)d_in[2];
    const float* Wq = (const float*)d_in[3];
    const float* bq = (const float*)d_in[4];
    const float* Wk = (const float*)d_in[5];
    const float* bk = (const float*)d_in[6];
    const float* Wv = (const float*)d_in[7];
    const float* bv = (const float*)d_in[8];
    const float* Wo = (const float*)d_in[9];
    const float* bo = (const float*)d_in[10];

    char* ws = (char*)d_ws;
    unsigned short* WqT   = (unsigned short*)(ws + ((size_t)0  << 20));  // 2 MB (x C_EXP)
    unsigned short* WkT   = (unsigned short*)(ws + ((size_t)2  << 20));  // 2 MB
    unsigned short* WvT   = (unsigned short*)(ws + ((size_t)4  << 20));  // 2 MB
    unsigned short* WoT   = (unsigned short*)(ws + ((size_t)6  << 20));  // 2 MB
    unsigned*       flagsW= (unsigned*)      (ws + ((size_t)8  << 20));  // 256 B (bitwords)
    unsigned short* CONV  = (unsigned short*)(ws + ((size_t)9  << 20));  // 16 MB (Vbf16 -> Qbf16 -> attnb)
    unsigned short* Qp    = (unsigned short*)(ws + ((size_t)25 << 20));  // 16 MB (pre-scaled Q)
    unsigned short* Kp    = (unsigned short*)(ws + ((size_t)41 << 20));  // 16 MB
    unsigned short* VTp   = (unsigned short*)(ws + ((size_t)57 << 20));  // 16 MB ([bh][v][s])

    const int n8 = 8192 * 1024 / 8;

    hipMemsetAsync(flagsW, 0, 64 * sizeof(unsigned), stream);

    // value -> bf16; K and V projections consume it
    cvt_kernel<<<2048, 256, 0, stream>>>(value, CONV, n8);
    wtrans_kernel<<<dim3(16, 16, 4), 256, 0, stream>>>(Wq, Wk, Wv, Wo, WqT, WkT, WvT, WoT);
    maskflag_kernel<<<2048, 256, 0, stream>>>(mask, flagsW);
    mm_kernel<0><<<512, 256, 0, stream>>>(CONV, WkT, bk, 1.0f, Kp);
    mm_kernel<1><<<512, 256, 0, stream>>>(CONV, WvT, bv, 1.0f, VTp);

    // query -> bf16 (reuses CONV; value-bf16 dead now)
    cvt_kernel<<<2048, 256, 0, stream>>>(query, CONV, n8);
    mm_kernel<0><<<512, 256, 0, stream>>>(CONV, WqT, bq, C_EXP, Qp);

    // attention writes attnb into CONV (query-bf16 dead now)
    attn_kernel<<<2048, 256, 0, stream>>>(Qp, Kp, VTp, mask, flagsW, CONV);

    mm_kernel<2><<<512, 256, 0, stream>>>(CONV, WoT, bo, 1.0f, (float*)d_out);
}

// Round 9
// 217.583 us; speedup vs baseline: 2.0334x; 1.0306x over previous
//
#include <hip/hip_runtime.h>

typedef __bf16 bf16x8 __attribute__((ext_vector_type(8)));
typedef __bf16 bf16x4 __attribute__((ext_vector_type(4)));
typedef float  f32x4  __attribute__((ext_vector_type(4)));
typedef int    i32x4  __attribute__((ext_vector_type(4)));

typedef __attribute__((address_space(1))) unsigned int as1_u32;
typedef __attribute__((address_space(3))) unsigned int as3_u32;

#define DEVI __device__ __forceinline__

DEVI unsigned short f2bf(float f) {
    union { float f; unsigned u; } v; v.f = f;
    unsigned r = (v.u + 0x7fffu + ((v.u >> 16) & 1u)) >> 16;
    return (unsigned short)r;
}

// direct global->LDS 16B: lane L's 16B lands at ldsbase + L*16
DEVI void gload16(const void* g, void* l) {
    __builtin_amdgcn_global_load_lds((const as1_u32*)g, (as3_u32*)l, 16, 0, 0);
}

// softmax(x/8) = exp2(x * 0.125 * log2(e)); scale folded into Q projection.
#define C_EXP 0.18033688011112042f
// -10000 * log2(e)
#define MASK_ADD (-14426.950408889634f)

// ---------------------------------------------------------------------------
// f32 -> bf16 bulk convert (n8 = elements/8)
// ---------------------------------------------------------------------------
__global__ __launch_bounds__(256) void cvt_kernel(const float* __restrict__ in,
                                                  unsigned short* __restrict__ out,
                                                  int n8) {
    const int stride = gridDim.x * 256;
    for (int idx = blockIdx.x * 256 + threadIdx.x; idx < n8; idx += stride) {
        const f32x4 a = *(const f32x4*)(in + (size_t)idx * 8);
        const f32x4 b = *(const f32x4*)(in + (size_t)idx * 8 + 4);
        union { bf16x4 v[2]; i32x4 q; } u;
        u.v[0] = __builtin_convertvector(a, bf16x4);
        u.v[1] = __builtin_convertvector(b, bf16x4);
        *(i32x4*)(out + (size_t)idx * 8) = u.q;
    }
}

// ---------------------------------------------------------------------------
// Transpose 4x (1024x1024) f32 -> bf16: WT[n][k] = W[k][n]*scale, z selects.
// ---------------------------------------------------------------------------
__global__ __launch_bounds__(256) void wtrans_kernel(const float* __restrict__ W0,
                                                     const float* __restrict__ W1,
                                                     const float* __restrict__ W2,
                                                     const float* __restrict__ W3,
                                                     unsigned short* __restrict__ T0,
                                                     unsigned short* __restrict__ T1,
                                                     unsigned short* __restrict__ T2,
                                                     unsigned short* __restrict__ T3) {
    __shared__ float tile[64][65];
    const float* W;
    unsigned short* WT;
    float scale = 1.0f;
    switch (blockIdx.z) {
        case 0:  W = W0; WT = T0; scale = C_EXP; break;
        case 1:  W = W1; WT = T1; break;
        case 2:  W = W2; WT = T2; break;
        default: W = W3; WT = T3; break;
    }
    const int k0 = blockIdx.x * 64, n0 = blockIdx.y * 64;
    const int i = threadIdx.x;
    const int c4 = (i & 15) * 4, rbase = i >> 4;
    for (int rr = 0; rr < 4; ++rr) {
        const int kl = rbase + rr * 16;
        const float4 v = *(const float4*)(W + (size_t)(k0 + kl) * 1024 + n0 + c4);
        tile[kl][c4 + 0] = v.x; tile[kl][c4 + 1] = v.y;
        tile[kl][c4 + 2] = v.z; tile[kl][c4 + 3] = v.w;
    }
    __syncthreads();
    for (int rr = 0; rr < 4; ++rr) {
        const int nl = rbase + rr * 16;
        ushort4 o;
        o.x = f2bf(tile[c4 + 0][nl] * scale); o.y = f2bf(tile[c4 + 1][nl] * scale);
        o.z = f2bf(tile[c4 + 2][nl] * scale); o.w = f2bf(tile[c4 + 3][nl] * scale);
        *(ushort4*)(WT + (size_t)(n0 + nl) * 1024 + k0 + c4) = o;
    }
}

// ---------------------------------------------------------------------------
// Mask not-all-true bits: word[(b*16+tb128)] bit si set if any zero in the
// (b, 128-row t-tile, 64-col s-tile). mask is int32. flagsW pre-zeroed.
// ---------------------------------------------------------------------------
__global__ __launch_bounds__(256) void maskflag_kernel(const int* __restrict__ mask,
                                                       unsigned* __restrict__ flagsW) {
    const int bid = blockIdx.x;
    const int b = bid >> 9, rem = bid & 511;
    const int tb = rem >> 5, si = rem & 31;
    const int i = threadIdx.x;
    const int t = tb * 128 + (i >> 1);
    const int s = si * 64 + (i & 1) * 32;
    const uint4* p = (const uint4*)(mask + ((size_t)(b * 2048 + t)) * 2048 + s);
    int ok = 1;
    #pragma unroll
    for (int u = 0; u < 8; ++u) {
        const uint4 a = p[u];
        ok &= (a.x != 0) & (a.y != 0) & (a.z != 0) & (a.w != 0);
    }
    int all = __syncthreads_and(ok);
    if (i == 0 && !all) atomicOr(&flagsW[b * 16 + tb], 1u << si);
}

// ---------------------------------------------------------------------------
// Unified bf16 GEMM, m97-style: C[m,n] = A[m,:] . BT[n,:] + bias[n]*bscale
// 128x128 tile, BK=32, 4 waves, global_load_lds w16, XCD-swizzled 1D grid.
// MODE 0: bf16 scatter [b][h][t][c];  MODE 1: bf16 V^T [b][h][c][t];
// MODE 2: f32 linear [m][n].
// ---------------------------------------------------------------------------
template <int MODE>
__global__ __launch_bounds__(256) void mm_kernel(const unsigned short* __restrict__ A,
                                                 const unsigned short* __restrict__ BT,
                                                 const float* __restrict__ bias,
                                                 float bscale,
                                                 void* __restrict__ Ov) {
    __shared__ __align__(16) unsigned short Ab[128 * 32];
    __shared__ __align__(16) unsigned short Bb[128 * 32];
    const int bid = blockIdx.x;
    const int xcd = bid & 7, jj = bid >> 3;
    const int n0 = (jj & 7) * 128;
    const int m0 = ((jj >> 3) * 8 + xcd) * 128;
    const int i = threadIdx.x, w = i >> 6, l = i & 63;
    const int wm = w >> 1, wn = w & 1;
    const int c = l & 15, g = l >> 4;
    const int rloc = l >> 2;
    const int schunk = ((l & 3) ^ ((l >> 3) & 3)) * 8;
    const int rs = (c >> 1) & 3;

    f32x4 acc[4][4] = {};

    const unsigned short* Asrc = A + (size_t)(m0 + w * 32 + rloc) * 1024 + schunk;
    const unsigned short* Bsrc = BT + (size_t)(n0 + w * 32 + rloc) * 1024 + schunk;
    unsigned short* AbBase = &Ab[(w * 32) * 32];
    unsigned short* BbBase = &Bb[(w * 32) * 32];

    for (int k0 = 0; k0 < 1024; k0 += 32) {
        gload16(Asrc + k0,             AbBase);
        gload16(Asrc + k0 + 16 * 1024, AbBase + 16 * 32);
        gload16(Bsrc + k0,             BbBase);
        gload16(Bsrc + k0 + 16 * 1024, BbBase + 16 * 32);
        __syncthreads();
        bf16x8 af[4], bfr[4];
        #pragma unroll
        for (int mf = 0; mf < 4; ++mf)
            af[mf] = *(const bf16x8*)&Ab[(wm * 64 + mf * 16 + c) * 32 + (g ^ rs) * 8];
        #pragma unroll
        for (int nf = 0; nf < 4; ++nf)
            bfr[nf] = *(const bf16x8*)&Bb[(wn * 64 + nf * 16 + c) * 32 + (g ^ rs) * 8];
        #pragma unroll
        for (int mf = 0; mf < 4; ++mf)
            #pragma unroll
            for (int nf = 0; nf < 4; ++nf)
                acc[mf][nf] = __builtin_amdgcn_mfma_f32_16x16x32_bf16(af[mf], bfr[nf], acc[mf][nf], 0, 0, 0);
        __syncthreads();
    }

    #pragma unroll
    for (int nf = 0; nf < 4; ++nf) {
        const int n = n0 + wn * 64 + nf * 16 + c;
        const float bv = bias[n] * bscale;
        const int h = n >> 6, cc = n & 63;
        #pragma unroll
        for (int mf = 0; mf < 4; ++mf) {
            const int mbase = m0 + wm * 64 + mf * 16 + g * 4;
            if (MODE == 0) {
                const int b = mbase >> 11, t = mbase & 2047;
                unsigned short* O = (unsigned short*)Ov;
                #pragma unroll
                for (int r = 0; r < 4; ++r)
                    O[(((size_t)(b * 16 + h)) * 2048 + t + r) * 64 + cc] = f2bf(acc[mf][nf][r] + bv);
            } else if (MODE == 1) {
                const int b = mbase >> 11, t = mbase & 2047;
                f32x4 v;
                #pragma unroll
                for (int r = 0; r < 4; ++r) v[r] = acc[mf][nf][r] + bv;
                bf16x4 pv = __builtin_convertvector(v, bf16x4);
                unsigned short* O = (unsigned short*)Ov;
                *(bf16x4*)(O + (((size_t)(b * 16 + h)) * 64 + cc) * 2048 + t) = pv;
            } else {
                float* O = (float*)Ov;
                #pragma unroll
                for (int r = 0; r < 4; ++r)
                    O[(size_t)(mbase + r) * 1024 + n] = acc[mf][nf][r] + bv;
            }
        }
    }
}

// ---------------------------------------------------------------------------
// Flash attention, swapped QK^T with PERMUTED K rows (P in registers, K32 PV).
// Each wave handles TWO 16-row t-groups (block = 128 Q rows, grid = 1024 =
// exactly 4 blocks/CU, no dispatch tail; LDS 4x32KB = 128KB). Shared kf/vf
// LDS reads feed both groups' MFMAs (16 b128 reads -> 36 MFMA per iter).
// Flags bitword granularity = one block. setprio around MFMA clusters.
// XCD swizzle: each XCD owns 8 bh x 16 tb (K/V 4MB = L2-resident).
// ---------------------------------------------------------------------------
__global__ __launch_bounds__(256, 4) void attn_kernel(const unsigned short* __restrict__ Qp,
                                                      const unsigned short* __restrict__ Kp,
                                                      const unsigned short* __restrict__ VTp,
                                                      const int* __restrict__ mask,
                                                      const unsigned* __restrict__ flagsW,
                                                      unsigned short* __restrict__ attnb) {
    __shared__ __align__(16) unsigned short Kt[2][64 * 64];  // [s][dk], swizzled chunks
    __shared__ __align__(16) unsigned short Vt[2][64 * 64];  // [v][s],  swizzled chunks

    const int bid = blockIdx.x;
    const int xcd = bid & 7, jj = bid >> 3;       // jj in 0..127
    const int bh = xcd * 8 + (jj >> 4);           // 8 bh per XCD
    const int tb = jj & 15;                       // 16 x 128-row t-tiles
    const int b = bh >> 4, h = bh & 15;
    const int i = threadIdx.x, w = i >> 6, l = i & 63;
    const int c = l & 15, g = l >> 4;

    const unsigned short* Qb  = Qp  + (size_t)bh * 2048 * 64;
    const unsigned short* Kb  = Kp  + (size_t)bh * 2048 * 64;
    const unsigned short* VTb = VTp + (size_t)bh * 64 * 2048;

    const int twave = tb * 128 + w * 32;
    const int tA = twave + c, tB = twave + 16 + c;

    // not-all-true bits for this 128-row region (wave-uniform, to SGPR)
    const unsigned notall = __builtin_amdgcn_readfirstlane(flagsW[b * 16 + tb]);

    // Q as B-operand (K32): lane holds Q[t][dk = kq*32+g*8+j]
    bf16x8 qfA[2], qfB[2];
    #pragma unroll
    for (int kq = 0; kq < 2; ++kq) {
        qfA[kq] = *(const bf16x8*)(Qb + (size_t)tA * 64 + kq * 32 + g * 8);
        qfB[kq] = *(const bf16x8*)(Qb + (size_t)tB * 64 + kq * 32 + g * 8);
    }

    f32x4 oA[4] = {}, oB[4] = {};   // O^T accum: v = vm*16+g*4+r
    f32x4 daccA = {}, daccB = {};   // denominators via ones-MFMA
    const f32x4 zf = {};            // persistent zero C-operand

    bf16x8 ones8;
    #pragma unroll
    for (int j = 0; j < 8; ++j) ones8[j] = (__bf16)1.0f;

    // kf read rows (permuted) + chunk swizzles, per sm
    int rrow[4], rswz[4];
    #pragma unroll
    for (int sm = 0; sm < 4; ++sm) {
        rrow[sm] = (sm >> 1) * 32 + (c >> 2) * 8 + (sm & 1) * 4 + (c & 3);
        rswz[sm] = (rrow[sm] ^ (rrow[sm] >> 2)) & 7;
    }
    int vswz[4];
    #pragma unroll
    for (int vm = 0; vm < 4; ++vm) {
        const int rv = vm * 16 + c;
        vswz[vm] = (rv ^ (rv >> 2)) & 7;
    }

    // staging: lane L -> LDS (row = base + L>>3, slot L&7); source chunk
    // = (L&7) ^ swz(row) so LDS slot s of row r holds global chunk s ^ swz(r).
    const int srow = l >> 3, sslot = l & 7;

    // prologue: stage tile 0 into buffer 0; running stage pointers (tile 1)
    const unsigned short* kstage[2];
    const unsigned short* vstage[2];
    #pragma unroll
    for (int u = 0; u < 2; ++u) {
        const int row = w * 16 + u * 8 + srow;
        const int ch = sslot ^ ((row ^ (row >> 2)) & 7);
        gload16(Kb + (size_t)row * 64 + ch * 8, &Kt[0][(w * 16 + u * 8) * 64]);
        gload16(VTb + (size_t)row * 2048 + ch * 8, &Vt[0][(w * 16 + u * 8) * 64]);
        kstage[u] = Kb + (size_t)(64 + row) * 64 + ch * 8;
        vstage[u] = VTb + (size_t)row * 2048 + 64 + ch * 8;
    }
    __syncthreads();

    #pragma unroll 2
    for (int it = 0; it < 32; ++it) {
        const int buf = it & 1;
        const int s0 = it * 64;

        // issue next-tile stage (lands in buf^1; drained by end-of-iter barrier)
        if (it < 31) {
            #pragma unroll
            for (int u = 0; u < 2; ++u) {
                gload16(kstage[u], &Kt[buf ^ 1][(w * 16 + u * 8) * 64]);
                gload16(vstage[u], &Vt[buf ^ 1][(w * 16 + u * 8) * 64]);
                kstage[u] += 64 * 64;
                vstage[u] += 64;
            }
        }

        // QK^T swapped, permuted rows, both groups sharing kf:
        // scX[sm][r] = S^T at s = s0 + (sm>>1)*32 + g*8 + (sm&1)*4 + r
        f32x4 scA[4], scB[4];
        __builtin_amdgcn_s_setprio(1);
        #pragma unroll
        for (int sm = 0; sm < 4; ++sm) {
            #pragma unroll
            for (int kq = 0; kq < 2; ++kq) {
                const bf16x8 kf = *(const bf16x8*)&Kt[buf][rrow[sm] * 64 + (((kq * 4 + g) ^ rswz[sm]) * 8)];
                if (kq == 0) {
                    scA[sm] = __builtin_amdgcn_mfma_f32_16x16x32_bf16(kf, qfA[0], zf, 0, 0, 0);
                    scB[sm] = __builtin_amdgcn_mfma_f32_16x16x32_bf16(kf, qfB[0], zf, 0, 0, 0);
                } else {
                    scA[sm] = __builtin_amdgcn_mfma_f32_16x16x32_bf16(kf, qfA[1], scA[sm], 0, 0, 0);
                    scB[sm] = __builtin_amdgcn_mfma_f32_16x16x32_bf16(kf, qfB[1], scB[sm], 0, 0, 0);
                }
            }
        }
        __builtin_amdgcn_s_setprio(0);

        // mask fallback (exp2 domain), permuted s indexing (scalar-skipped)
        if (notall & (1u << it)) {
            #pragma unroll
            for (int sm = 0; sm < 4; ++sm)
                #pragma unroll
                for (int r = 0; r < 4; ++r) {
                    const int s = s0 + (sm >> 1) * 32 + g * 8 + (sm & 1) * 4 + r;
                    if (mask[(size_t)(b * 2048 + tA) * 2048 + s] == 0) scA[sm][r] += MASK_ADD;
                    if (mask[(size_t)(b * 2048 + tB) * 2048 + s] == 0) scB[sm][r] += MASK_ADD;
                }
        }

        // p = exp2(sc); pack directly into K32 PV B-fragments
        bf16x8 paA[2], paB[2];
        #pragma unroll
        for (int kv = 0; kv < 2; ++kv) {
            f32x4 a0, a1, b0, b1;
            #pragma unroll
            for (int r = 0; r < 4; ++r) {
                a0[r] = __builtin_amdgcn_exp2f(scA[kv * 2][r]);
                a1[r] = __builtin_amdgcn_exp2f(scA[kv * 2 + 1][r]);
                b0[r] = __builtin_amdgcn_exp2f(scB[kv * 2][r]);
                b1[r] = __builtin_amdgcn_exp2f(scB[kv * 2 + 1][r]);
            }
            union { struct { bf16x4 lo, hi; } hh; bf16x8 v; } ua, ub;
            ua.hh.lo = __builtin_convertvector(a0, bf16x4);
            ua.hh.hi = __builtin_convertvector(a1, bf16x4);
            ub.hh.lo = __builtin_convertvector(b0, bf16x4);
            ub.hh.hi = __builtin_convertvector(b1, bf16x4);
            paA[kv] = ua.v;
            paB[kv] = ub.v;
        }

        // PV (K32) + denominators, shared vf
        __builtin_amdgcn_s_setprio(1);
        #pragma unroll
        for (int kv = 0; kv < 2; ++kv) {
            daccA = __builtin_amdgcn_mfma_f32_16x16x32_bf16(ones8, paA[kv], daccA, 0, 0, 0);
            daccB = __builtin_amdgcn_mfma_f32_16x16x32_bf16(ones8, paB[kv], daccB, 0, 0, 0);
            #pragma unroll
            for (int vm = 0; vm < 4; ++vm) {
                const bf16x8 vf = *(const bf16x8*)&Vt[buf][(vm * 16 + c) * 64 + (((kv * 4 + g) ^ vswz[vm]) * 8)];
                oA[vm] = __builtin_amdgcn_mfma_f32_16x16x32_bf16(vf, paA[kv], oA[vm], 0, 0, 0);
                oB[vm] = __builtin_amdgcn_mfma_f32_16x16x32_bf16(vf, paB[kv], oB[vm], 0, 0, 0);
            }
        }
        __builtin_amdgcn_s_setprio(0);

        __syncthreads();  // drains vmcnt (stage) + lgkm, then barrier
    }

    const float invA = 1.0f / daccA[0];
    const float invB = 1.0f / daccB[0];

    // epilogue: attnb[(b*2048+t)*1024 + h*64 + v] = O^T[v][t] * inv
    #pragma unroll
    for (int vm = 0; vm < 4; ++vm) {
        f32x4 vA, vB;
        #pragma unroll
        for (int r = 0; r < 4; ++r) { vA[r] = oA[vm][r] * invA; vB[r] = oB[vm][r] * invB; }
        bf16x4 pA = __builtin_convertvector(vA, bf16x4);
        bf16x4 pB = __builtin_convertvector(vB, bf16x4);
        *(bf16x4*)(attnb + (size_t)(b * 2048 + tA) * 1024 + h * 64 + vm * 16 + g * 4) = pA;
        *(bf16x4*)(attnb + (size_t)(b * 2048 + tB) * 1024 + h * 64 + vm * 16 + g * 4) = pB;
    }
}

// ---------------------------------------------------------------------------
extern "C" void kernel_launch(void* const* d_in, const int* in_sizes, int n_in,
                              void* d_out, int out_size, void* d_ws, size_t ws_size,
                              hipStream_t stream) {
    const float* query = (const float*)d_in[0];
    const float* value = (const float*)d_in[1];
    const int*   mask  = (const int*)d_in[2];
    const float* Wq = (const float*)d_in[3];
    const float* bq = (const float*)d_in[4];
    const float* Wk = (const float*)d_in[5];
    const float* bk = (const float*)d_in[6];
    const float* Wv = (const float*)d_in[7];
    const float* bv = (const float*)d_in[8];
    const float* Wo = (const float*)d_in[9];
    const float* bo = (const float*)d_in[10];

    char* ws = (char*)d_ws;
    unsigned short* WqT   = (unsigned short*)(ws + ((size_t)0  << 20));  // 2 MB (x C_EXP)
    unsigned short* WkT   = (unsigned short*)(ws + ((size_t)2  << 20));  // 2 MB
    unsigned short* WvT   = (unsigned short*)(ws + ((size_t)4  << 20));  // 2 MB
    unsigned short* WoT   = (unsigned short*)(ws + ((size_t)6  << 20));  // 2 MB
    unsigned*       flagsW= (unsigned*)      (ws + ((size_t)8  << 20));  // 256 B (bitwords)
    unsigned short* CONV  = (unsigned short*)(ws + ((size_t)9  << 20));  // 16 MB (Vbf16 -> Qbf16 -> attnb)
    unsigned short* Qp    = (unsigned short*)(ws + ((size_t)25 << 20));  // 16 MB (pre-scaled Q)
    unsigned short* Kp    = (unsigned short*)(ws + ((size_t)41 << 20));  // 16 MB
    unsigned short* VTp   = (unsigned short*)(ws + ((size_t)57 << 20));  // 16 MB ([bh][v][s])

    const int n8 = 8192 * 1024 / 8;

    hipMemsetAsync(flagsW, 0, 64 * sizeof(unsigned), stream);

    // value -> bf16; K and V projections consume it
    cvt_kernel<<<2048, 256, 0, stream>>>(value, CONV, n8);
    wtrans_kernel<<<dim3(16, 16, 4), 256, 0, stream>>>(Wq, Wk, Wv, Wo, WqT, WkT, WvT, WoT);
    maskflag_kernel<<<2048, 256, 0, stream>>>(mask, flagsW);
    mm_kernel<0><<<512, 256, 0, stream>>>(CONV, WkT, bk, 1.0f, Kp);
    mm_kernel<1><<<512, 256, 0, stream>>>(CONV, WvT, bv, 1.0f, VTp);

    // query -> bf16 (reuses CONV; value-bf16 dead now)
    cvt_kernel<<<2048, 256, 0, stream>>>(query, CONV, n8);
    mm_kernel<0><<<512, 256, 0, stream>>>(CONV, WqT, bq, C_EXP, Qp);

    // attention writes attnb into CONV (query-bf16 dead now)
    attn_kernel<<<1024, 256, 0, stream>>>(Qp, Kp, VTp, mask, flagsW, CONV);

    mm_kernel<2><<<512, 256, 0, stream>>>(CONV, WoT, bo, 1.0f, (float*)d_out);
}

// Round 10
// 204.468 us; speedup vs baseline: 2.1639x; 1.0641x over previous
//
#include <hip/hip_runtime.h>

typedef __bf16 bf16x8 __attribute__((ext_vector_type(8)));
typedef __bf16 bf16x4 __attribute__((ext_vector_type(4)));
typedef float  f32x4  __attribute__((ext_vector_type(4)));
typedef int    i32x4  __attribute__((ext_vector_type(4)));

typedef __attribute__((address_space(1))) unsigned int as1_u32;
typedef __attribute__((address_space(3))) unsigned int as3_u32;

#define DEVI __device__ __forceinline__

DEVI unsigned short f2bf(float f) {
    union { float f; unsigned u; } v; v.f = f;
    unsigned r = (v.u + 0x7fffu + ((v.u >> 16) & 1u)) >> 16;
    return (unsigned short)r;
}

// direct global->LDS 16B: lane L's 16B lands at ldsbase + L*16
DEVI void gload16(const void* g, void* l) {
    __builtin_amdgcn_global_load_lds((const as1_u32*)g, (as3_u32*)l, 16, 0, 0);
}

// softmax(x/8) = exp2(x * 0.125 * log2(e)); scale folded into Q projection.
#define C_EXP 0.18033688011112042f
// -10000 * log2(e)
#define MASK_ADD (-14426.950408889634f)

// ---------------------------------------------------------------------------
// f32 -> bf16 bulk convert (n8 = elements/8)
// ---------------------------------------------------------------------------
__global__ __launch_bounds__(256) void cvt_kernel(const float* __restrict__ in,
                                                  unsigned short* __restrict__ out,
                                                  int n8) {
    const int stride = gridDim.x * 256;
    for (int idx = blockIdx.x * 256 + threadIdx.x; idx < n8; idx += stride) {
        const f32x4 a = *(const f32x4*)(in + (size_t)idx * 8);
        const f32x4 b = *(const f32x4*)(in + (size_t)idx * 8 + 4);
        union { bf16x4 v[2]; i32x4 q; } u;
        u.v[0] = __builtin_convertvector(a, bf16x4);
        u.v[1] = __builtin_convertvector(b, bf16x4);
        *(i32x4*)(out + (size_t)idx * 8) = u.q;
    }
}

// ---------------------------------------------------------------------------
// Transpose 4x (1024x1024) f32 -> bf16: WT[n][k] = W[k][n]*scale, z selects.
// ---------------------------------------------------------------------------
__global__ __launch_bounds__(256) void wtrans_kernel(const float* __restrict__ W0,
                                                     const float* __restrict__ W1,
                                                     const float* __restrict__ W2,
                                                     const float* __restrict__ W3,
                                                     unsigned short* __restrict__ T0,
                                                     unsigned short* __restrict__ T1,
                                                     unsigned short* __restrict__ T2,
                                                     unsigned short* __restrict__ T3) {
    __shared__ float tile[64][65];
    const float* W;
    unsigned short* WT;
    float scale = 1.0f;
    switch (blockIdx.z) {
        case 0:  W = W0; WT = T0; scale = C_EXP; break;
        case 1:  W = W1; WT = T1; break;
        case 2:  W = W2; WT = T2; break;
        default: W = W3; WT = T3; break;
    }
    const int k0 = blockIdx.x * 64, n0 = blockIdx.y * 64;
    const int i = threadIdx.x;
    const int c4 = (i & 15) * 4, rbase = i >> 4;
    for (int rr = 0; rr < 4; ++rr) {
        const int kl = rbase + rr * 16;
        const float4 v = *(const float4*)(W + (size_t)(k0 + kl) * 1024 + n0 + c4);
        tile[kl][c4 + 0] = v.x; tile[kl][c4 + 1] = v.y;
        tile[kl][c4 + 2] = v.z; tile[kl][c4 + 3] = v.w;
    }
    __syncthreads();
    for (int rr = 0; rr < 4; ++rr) {
        const int nl = rbase + rr * 16;
        ushort4 o;
        o.x = f2bf(tile[c4 + 0][nl] * scale); o.y = f2bf(tile[c4 + 1][nl] * scale);
        o.z = f2bf(tile[c4 + 2][nl] * scale); o.w = f2bf(tile[c4 + 3][nl] * scale);
        *(ushort4*)(WT + (size_t)(n0 + nl) * 1024 + k0 + c4) = o;
    }
}

// ---------------------------------------------------------------------------
// Mask not-all-true bits: word[(b*16+tb128)] bit si set if any zero in the
// (b, 128-row t-tile, 64-col s-tile). mask is int32. flagsW pre-zeroed.
// ---------------------------------------------------------------------------
__global__ __launch_bounds__(256) void maskflag_kernel(const int* __restrict__ mask,
                                                       unsigned* __restrict__ flagsW) {
    const int bid = blockIdx.x;
    const int b = bid >> 9, rem = bid & 511;
    const int tb = rem >> 5, si = rem & 31;
    const int i = threadIdx.x;
    const int t = tb * 128 + (i >> 1);
    const int s = si * 64 + (i & 1) * 32;
    const uint4* p = (const uint4*)(mask + ((size_t)(b * 2048 + t)) * 2048 + s);
    int ok = 1;
    #pragma unroll
    for (int u = 0; u < 8; ++u) {
        const uint4 a = p[u];
        ok &= (a.x != 0) & (a.y != 0) & (a.z != 0) & (a.w != 0);
    }
    int all = __syncthreads_and(ok);
    if (i == 0 && !all) atomicOr(&flagsW[b * 16 + tb], 1u << si);
}

// ---------------------------------------------------------------------------
// Unified bf16 GEMM: C[m,n] = A[m,:] . BT[n,:] + bias[n]*bscale
// 128x128 tile, BK=64, DOUBLE-BUFFERED global_load_lds staging (stage k+1
// issued before compute of k -> latency hidden under 32 MFMA + 16 ds_read).
// XOR chunk-swizzle (swz(r) = (r^(r>>2))&7) on both stage source and reads.
// XCD-swizzled 1D grid: NB n-blocks per m-panel land on one XCD.
// MODE 0: bf16 scatter [b][h][t][c]        (Q)
// MODE 2: f32 linear [m][n]                (output)
// MODE 3: merged K|V: n<1024 -> K scatter; n>=1024 -> V^T scatter.
// ---------------------------------------------------------------------------
template <int MODE, int NB>
__global__ __launch_bounds__(256) void mm_kernel(const unsigned short* __restrict__ A,
                                                 const unsigned short* __restrict__ BT,
                                                 const float* __restrict__ biasK,
                                                 const float* __restrict__ biasV,
                                                 float bscale,
                                                 void* __restrict__ OvK,
                                                 void* __restrict__ OvV) {
    __shared__ __align__(16) unsigned short Ab[2][128 * 64];
    __shared__ __align__(16) unsigned short Bb[2][128 * 64];
    const int bid = blockIdx.x;
    const int xcd = bid & 7, jj = bid >> 3;
    const int n0 = (jj % NB) * 128;
    const int m0 = ((jj / NB) * 8 + xcd) * 128;
    const int i = threadIdx.x, w = i >> 6, l = i & 63;
    const int wm = w >> 1, wn = w & 1;
    const int c = l & 15, g = l >> 4;
    const int srow = l >> 3, sslot = l & 7;

    f32x4 acc[4][4] = {};

    // staging sources: wave w stages rows [w*32, w*32+32), 8 rows per gload.
    // LDS slot s of row r holds global chunk s ^ swz(r), swz(r)=(r^(r>>2))&7.
    const unsigned short* As[4];
    const unsigned short* Bs[4];
    unsigned lofs[4];
    #pragma unroll
    for (int u = 0; u < 4; ++u) {
        const int rl = w * 32 + u * 8 + srow;
        const int ch = sslot ^ ((rl ^ (rl >> 2)) & 7);
        As[u] = A  + (size_t)(m0 + rl) * 1024 + ch * 8;
        Bs[u] = BT + (size_t)(n0 + rl) * 1024 + ch * 8;
        lofs[u] = (unsigned)((w * 32 + u * 8) * 64);
    }

    // prologue: stage k-tile 0 into buffer 0
    #pragma unroll
    for (int u = 0; u < 4; ++u) {
        gload16(As[u], &Ab[0][lofs[u]]);
        gload16(Bs[u], &Bb[0][lofs[u]]);
    }
    __syncthreads();

    // read-side row swizzles
    int rsA[4], rsB[4];
    #pragma unroll
    for (int f = 0; f < 4; ++f) {
        const int ra = wm * 64 + f * 16 + c;
        const int rb = wn * 64 + f * 16 + c;
        rsA[f] = (ra ^ (ra >> 2)) & 7;
        rsB[f] = (rb ^ (rb >> 2)) & 7;
    }

    #pragma unroll 2
    for (int it = 0; it < 16; ++it) {
        const int buf = it & 1;
        // issue next k-tile stage (lands in buf^1; drained by end barrier)
        if (it < 15) {
            #pragma unroll
            for (int u = 0; u < 4; ++u) {
                gload16(As[u] + (it + 1) * 64, &Ab[buf ^ 1][lofs[u]]);
                gload16(Bs[u] + (it + 1) * 64, &Bb[buf ^ 1][lofs[u]]);
            }
        }
        bf16x8 af[4][2], bfr[4][2];
        #pragma unroll
        for (int f = 0; f < 4; ++f)
            #pragma unroll
            for (int kk = 0; kk < 2; ++kk) {
                af[f][kk]  = *(const bf16x8*)&Ab[buf][(wm * 64 + f * 16 + c) * 64 + (((kk * 4 + g) ^ rsA[f]) * 8)];
                bfr[f][kk] = *(const bf16x8*)&Bb[buf][(wn * 64 + f * 16 + c) * 64 + (((kk * 4 + g) ^ rsB[f]) * 8)];
            }
        __builtin_amdgcn_s_setprio(1);
        #pragma unroll
        for (int kk = 0; kk < 2; ++kk)
            #pragma unroll
            for (int mf = 0; mf < 4; ++mf)
                #pragma unroll
                for (int nf = 0; nf < 4; ++nf)
                    acc[mf][nf] = __builtin_amdgcn_mfma_f32_16x16x32_bf16(af[mf][kk], bfr[nf][kk], acc[mf][nf], 0, 0, 0);
        __builtin_amdgcn_s_setprio(0);
        __syncthreads();  // drains vmcnt (next tile) + lgkm, then barrier
    }

    #pragma unroll
    for (int nf = 0; nf < 4; ++nf) {
        const int n = n0 + wn * 64 + nf * 16 + c;
        if (MODE == 0 || (MODE == 3 && n0 < 1024)) {
            const float bv = biasK[n] * bscale;
            const int h = n >> 6, cc = n & 63;
            unsigned short* O = (unsigned short*)OvK;
            #pragma unroll
            for (int mf = 0; mf < 4; ++mf) {
                const int mbase = m0 + wm * 64 + mf * 16 + g * 4;
                const int b = mbase >> 11, t = mbase & 2047;
                #pragma unroll
                for (int r = 0; r < 4; ++r)
                    O[(((size_t)(b * 16 + h)) * 2048 + t + r) * 64 + cc] = f2bf(acc[mf][nf][r] + bv);
            }
        } else if (MODE == 3) {
            const int nn = n - 1024;
            const float bv = biasV[nn];
            const int h = nn >> 6, cc = nn & 63;
            unsigned short* O = (unsigned short*)OvV;
            #pragma unroll
            for (int mf = 0; mf < 4; ++mf) {
                const int mbase = m0 + wm * 64 + mf * 16 + g * 4;
                const int b = mbase >> 11, t = mbase & 2047;
                f32x4 v;
                #pragma unroll
                for (int r = 0; r < 4; ++r) v[r] = acc[mf][nf][r] + bv;
                bf16x4 pv = __builtin_convertvector(v, bf16x4);
                *(bf16x4*)(O + (((size_t)(b * 16 + h)) * 64 + cc) * 2048 + t) = pv;
            }
        } else {
            const float bv = biasK[n] * bscale;
            float* O = (float*)OvK;
            #pragma unroll
            for (int mf = 0; mf < 4; ++mf) {
                const int mbase = m0 + wm * 64 + mf * 16 + g * 4;
                #pragma unroll
                for (int r = 0; r < 4; ++r)
                    O[(size_t)(mbase + r) * 1024 + n] = acc[mf][nf][r] + bv;
            }
        }
    }
}

// ---------------------------------------------------------------------------
// Flash attention, swapped QK^T with PERMUTED K rows (P in registers, K32 PV).
// Each wave handles TWO 16-row t-groups (block = 128 Q rows, grid = 1024 =
// 4 blocks/CU; LDS 4x32KB = 128KB). Shared kf/vf LDS reads feed both groups.
// Flags bitword granularity = one block. setprio around MFMA clusters.
// XCD swizzle: each XCD owns 8 bh x 16 tb (K/V 4MB = L2-resident).
// ---------------------------------------------------------------------------
__global__ __launch_bounds__(256, 4) void attn_kernel(const unsigned short* __restrict__ Qp,
                                                      const unsigned short* __restrict__ Kp,
                                                      const unsigned short* __restrict__ VTp,
                                                      const int* __restrict__ mask,
                                                      const unsigned* __restrict__ flagsW,
                                                      unsigned short* __restrict__ attnb) {
    __shared__ __align__(16) unsigned short Kt[2][64 * 64];  // [s][dk], swizzled chunks
    __shared__ __align__(16) unsigned short Vt[2][64 * 64];  // [v][s],  swizzled chunks

    const int bid = blockIdx.x;
    const int xcd = bid & 7, jj = bid >> 3;       // jj in 0..127
    const int bh = xcd * 8 + (jj >> 4);           // 8 bh per XCD
    const int tb = jj & 15;                       // 16 x 128-row t-tiles
    const int b = bh >> 4, h = bh & 15;
    const int i = threadIdx.x, w = i >> 6, l = i & 63;
    const int c = l & 15, g = l >> 4;

    const unsigned short* Qb  = Qp  + (size_t)bh * 2048 * 64;
    const unsigned short* Kb  = Kp  + (size_t)bh * 2048 * 64;
    const unsigned short* VTb = VTp + (size_t)bh * 64 * 2048;

    const int twave = tb * 128 + w * 32;
    const int tA = twave + c, tB = twave + 16 + c;

    // not-all-true bits for this 128-row region (wave-uniform, to SGPR)
    const unsigned notall = __builtin_amdgcn_readfirstlane(flagsW[b * 16 + tb]);

    // Q as B-operand (K32): lane holds Q[t][dk = kq*32+g*8+j]
    bf16x8 qfA[2], qfB[2];
    #pragma unroll
    for (int kq = 0; kq < 2; ++kq) {
        qfA[kq] = *(const bf16x8*)(Qb + (size_t)tA * 64 + kq * 32 + g * 8);
        qfB[kq] = *(const bf16x8*)(Qb + (size_t)tB * 64 + kq * 32 + g * 8);
    }

    f32x4 oA[4] = {}, oB[4] = {};   // O^T accum: v = vm*16+g*4+r
    f32x4 daccA = {}, daccB = {};   // denominators via ones-MFMA
    const f32x4 zf = {};            // persistent zero C-operand

    bf16x8 ones8;
    #pragma unroll
    for (int j = 0; j < 8; ++j) ones8[j] = (__bf16)1.0f;

    // kf read rows (permuted) + chunk swizzles, per sm
    int rrow[4], rswz[4];
    #pragma unroll
    for (int sm = 0; sm < 4; ++sm) {
        rrow[sm] = (sm >> 1) * 32 + (c >> 2) * 8 + (sm & 1) * 4 + (c & 3);
        rswz[sm] = (rrow[sm] ^ (rrow[sm] >> 2)) & 7;
    }
    int vswz[4];
    #pragma unroll
    for (int vm = 0; vm < 4; ++vm) {
        const int rv = vm * 16 + c;
        vswz[vm] = (rv ^ (rv >> 2)) & 7;
    }

    // staging: lane L -> LDS (row = base + L>>3, slot L&7); source chunk
    // = (L&7) ^ swz(row) so LDS slot s of row r holds global chunk s ^ swz(r).
    const int srow = l >> 3, sslot = l & 7;

    // prologue: stage tile 0 into buffer 0; running stage pointers (tile 1)
    const unsigned short* kstage[2];
    const unsigned short* vstage[2];
    #pragma unroll
    for (int u = 0; u < 2; ++u) {
        const int row = w * 16 + u * 8 + srow;
        const int ch = sslot ^ ((row ^ (row >> 2)) & 7);
        gload16(Kb + (size_t)row * 64 + ch * 8, &Kt[0][(w * 16 + u * 8) * 64]);
        gload16(VTb + (size_t)row * 2048 + ch * 8, &Vt[0][(w * 16 + u * 8) * 64]);
        kstage[u] = Kb + (size_t)(64 + row) * 64 + ch * 8;
        vstage[u] = VTb + (size_t)row * 2048 + 64 + ch * 8;
    }
    __syncthreads();

    #pragma unroll 2
    for (int it = 0; it < 32; ++it) {
        const int buf = it & 1;
        const int s0 = it * 64;

        // issue next-tile stage (lands in buf^1; drained by end-of-iter barrier)
        if (it < 31) {
            #pragma unroll
            for (int u = 0; u < 2; ++u) {
                gload16(kstage[u], &Kt[buf ^ 1][(w * 16 + u * 8) * 64]);
                gload16(vstage[u], &Vt[buf ^ 1][(w * 16 + u * 8) * 64]);
                kstage[u] += 64 * 64;
                vstage[u] += 64;
            }
        }

        // QK^T swapped, permuted rows, both groups sharing kf:
        // scX[sm][r] = S^T at s = s0 + (sm>>1)*32 + g*8 + (sm&1)*4 + r
        f32x4 scA[4], scB[4];
        __builtin_amdgcn_s_setprio(1);
        #pragma unroll
        for (int sm = 0; sm < 4; ++sm) {
            #pragma unroll
            for (int kq = 0; kq < 2; ++kq) {
                const bf16x8 kf = *(const bf16x8*)&Kt[buf][rrow[sm] * 64 + (((kq * 4 + g) ^ rswz[sm]) * 8)];
                if (kq == 0) {
                    scA[sm] = __builtin_amdgcn_mfma_f32_16x16x32_bf16(kf, qfA[0], zf, 0, 0, 0);
                    scB[sm] = __builtin_amdgcn_mfma_f32_16x16x32_bf16(kf, qfB[0], zf, 0, 0, 0);
                } else {
                    scA[sm] = __builtin_amdgcn_mfma_f32_16x16x32_bf16(kf, qfA[1], scA[sm], 0, 0, 0);
                    scB[sm] = __builtin_amdgcn_mfma_f32_16x16x32_bf16(kf, qfB[1], scB[sm], 0, 0, 0);
                }
            }
        }
        __builtin_amdgcn_s_setprio(0);

        // mask fallback (exp2 domain), permuted s indexing (scalar-skipped)
        if (notall & (1u << it)) {
            #pragma unroll
            for (int sm = 0; sm < 4; ++sm)
                #pragma unroll
                for (int r = 0; r < 4; ++r) {
                    const int s = s0 + (sm >> 1) * 32 + g * 8 + (sm & 1) * 4 + r;
                    if (mask[(size_t)(b * 2048 + tA) * 2048 + s] == 0) scA[sm][r] += MASK_ADD;
                    if (mask[(size_t)(b * 2048 + tB) * 2048 + s] == 0) scB[sm][r] += MASK_ADD;
                }
        }

        // p = exp2(sc); pack directly into K32 PV B-fragments
        bf16x8 paA[2], paB[2];
        #pragma unroll
        for (int kv = 0; kv < 2; ++kv) {
            f32x4 a0, a1, b0, b1;
            #pragma unroll
            for (int r = 0; r < 4; ++r) {
                a0[r] = __builtin_amdgcn_exp2f(scA[kv * 2][r]);
                a1[r] = __builtin_amdgcn_exp2f(scA[kv * 2 + 1][r]);
                b0[r] = __builtin_amdgcn_exp2f(scB[kv * 2][r]);
                b1[r] = __builtin_amdgcn_exp2f(scB[kv * 2 + 1][r]);
            }
            union { struct { bf16x4 lo, hi; } hh; bf16x8 v; } ua, ub;
            ua.hh.lo = __builtin_convertvector(a0, bf16x4);
            ua.hh.hi = __builtin_convertvector(a1, bf16x4);
            ub.hh.lo = __builtin_convertvector(b0, bf16x4);
            ub.hh.hi = __builtin_convertvector(b1, bf16x4);
            paA[kv] = ua.v;
            paB[kv] = ub.v;
        }

        // PV (K32) + denominators, shared vf
        __builtin_amdgcn_s_setprio(1);
        #pragma unroll
        for (int kv = 0; kv < 2; ++kv) {
            daccA = __builtin_amdgcn_mfma_f32_16x16x32_bf16(ones8, paA[kv], daccA, 0, 0, 0);
            daccB = __builtin_amdgcn_mfma_f32_16x16x32_bf16(ones8, paB[kv], daccB, 0, 0, 0);
            #pragma unroll
            for (int vm = 0; vm < 4; ++vm) {
                const bf16x8 vf = *(const bf16x8*)&Vt[buf][(vm * 16 + c) * 64 + (((kv * 4 + g) ^ vswz[vm]) * 8)];
                oA[vm] = __builtin_amdgcn_mfma_f32_16x16x32_bf16(vf, paA[kv], oA[vm], 0, 0, 0);
                oB[vm] = __builtin_amdgcn_mfma_f32_16x16x32_bf16(vf, paB[kv], oB[vm], 0, 0, 0);
            }
        }
        __builtin_amdgcn_s_setprio(0);

        __syncthreads();  // drains vmcnt (stage) + lgkm, then barrier
    }

    const float invA = 1.0f / daccA[0];
    const float invB = 1.0f / daccB[0];

    // epilogue: attnb[(b*2048+t)*1024 + h*64 + v] = O^T[v][t] * inv
    #pragma unroll
    for (int vm = 0; vm < 4; ++vm) {
        f32x4 vA, vB;
        #pragma unroll
        for (int r = 0; r < 4; ++r) { vA[r] = oA[vm][r] * invA; vB[r] = oB[vm][r] * invB; }
        bf16x4 pA = __builtin_convertvector(vA, bf16x4);
        bf16x4 pB = __builtin_convertvector(vB, bf16x4);
        *(bf16x4*)(attnb + (size_t)(b * 2048 + tA) * 1024 + h * 64 + vm * 16 + g * 4) = pA;
        *(bf16x4*)(attnb + (size_t)(b * 2048 + tB) * 1024 + h * 64 + vm * 16 + g * 4) = pB;
    }
}

// ---------------------------------------------------------------------------
extern "C" void kernel_launch(void* const* d_in, const int* in_sizes, int n_in,
                              void* d_out, int out_size, void* d_ws, size_t ws_size,
                              hipStream_t stream) {
    const float* query = (const float*)d_in[0];
    const float* value = (const float*)d_in[1];
    const int*   mask  = (const int*)d_in[2];
    const float* Wq = (const float*)d_in[3];
    const float* bq = (const float*)d_in[4];
    const float* Wk = (const float*)d_in[5];
    const float* bk = (const float*)d_in[6];
    const float* Wv = (const float*)d_in[7];
    const float* bv = (const float*)d_in[8];
    const float* Wo = (const float*)d_in[9];
    const float* bo = (const float*)d_in[10];

    char* ws = (char*)d_ws;
    unsigned short* WqT   = (unsigned short*)(ws + ((size_t)0  << 20));  // 2 MB (x C_EXP)
    unsigned short* WkT   = (unsigned short*)(ws + ((size_t)2  << 20));  // 2 MB  } contiguous ->
    unsigned short* WvT   = (unsigned short*)(ws + ((size_t)4  << 20));  // 2 MB  } stacked KV BT
    unsigned short* WoT   = (unsigned short*)(ws + ((size_t)6  << 20));  // 2 MB
    unsigned*       flagsW= (unsigned*)      (ws + ((size_t)8  << 20));  // 256 B (bitwords)
    unsigned short* CONV  = (unsigned short*)(ws + ((size_t)9  << 20));  // 16 MB (Vbf16 -> Qbf16 -> attnb)
    unsigned short* Qp    = (unsigned short*)(ws + ((size_t)25 << 20));  // 16 MB (pre-scaled Q)
    unsigned short* Kp    = (unsigned short*)(ws + ((size_t)41 << 20));  // 16 MB
    unsigned short* VTp   = (unsigned short*)(ws + ((size_t)57 << 20));  // 16 MB ([bh][v][s])

    const int n8 = 8192 * 1024 / 8;

    hipMemsetAsync(flagsW, 0, 64 * sizeof(unsigned), stream);

    // value -> bf16; merged K|V projection consumes it (BT = WkT||WvT stacked)
    cvt_kernel<<<2048, 256, 0, stream>>>(value, CONV, n8);
    wtrans_kernel<<<dim3(16, 16, 4), 256, 0, stream>>>(Wq, Wk, Wv, Wo, WqT, WkT, WvT, WoT);
    maskflag_kernel<<<2048, 256, 0, stream>>>(mask, flagsW);
    mm_kernel<3, 16><<<1024, 256, 0, stream>>>(CONV, WkT, bk, bv, 1.0f, Kp, VTp);

    // query -> bf16 (reuses CONV; value-bf16 dead now)
    cvt_kernel<<<2048, 256, 0, stream>>>(query, CONV, n8);
    mm_kernel<0, 8><<<512, 256, 0, stream>>>(CONV, WqT, bq, bq, C_EXP, Qp, nullptr);

    // attention writes attnb into CONV (query-bf16 dead now)
    attn_kernel<<<1024, 256, 0, stream>>>(Qp, Kp, VTp, mask, flagsW, CONV);

    mm_kernel<2, 8><<<512, 256, 0, stream>>>(CONV, WoT, bo, bo, 1.0f, d_out, nullptr);
}